// Round 6
// baseline (743.227 us; speedup 1.0000x reference)
//
#include <hip/hip_runtime.h>
#include <hip/hip_bf16.h>
#include <cstdint>

#define N_NODES 100000
#define N_EDGES 800000
#define CH      256
#define COUT    40
#define COUTP   64   // padded out-channels; 128B = one cache line per row
#define EPS     1e-5f
#define SCAN_CHUNK 1024
#define NSCAN_BLK  98   // ceil(100000/1024)
#define AGG_NPW 16      // nodes per wave in k_agg (strided)
#define AGG_BLOCKS 2048 // full residency: 8 blocks/CU * 256 CU
#define AGG_WAVES  (AGG_BLOCKS * 4)   // 8192 waves; stride for node assignment

typedef unsigned short u16;
typedef unsigned int   u32;
typedef short s16x8 __attribute__((ext_vector_type(8)));
typedef float f32x4 __attribute__((ext_vector_type(4)));

__device__ __forceinline__ float b2f(u32 u) { return __uint_as_float(u << 16); }
__device__ __forceinline__ u16 f2b(float f) {
    u32 u = __float_as_uint(f);
    u32 r = (u + 0x7fffu + ((u >> 16) & 1u)) >> 16;   // RNE
    return (u16)r;
}
__device__ __forceinline__ u32 packb(float a, float b) {
    return (u32)f2b(a) | ((u32)f2b(b) << 16);
}
__device__ __forceinline__ void unpack8(uint4 v, float* f) {
    f[0] = b2f(v.x & 0xffffu); f[1] = b2f(v.x >> 16);
    f[2] = b2f(v.y & 0xffffu); f[3] = b2f(v.y >> 16);
    f[4] = b2f(v.z & 0xffffu); f[5] = b2f(v.z >> 16);
    f[6] = b2f(v.w & 0xffffu); f[7] = b2f(v.w >> 16);
}

// ---------------- CSR build ----------------
__global__ void k_count(const int* __restrict__ dst, int* __restrict__ counts) {
    int e = blockIdx.x * 256 + threadIdx.x;
    if (e < N_EDGES) atomicAdd(&counts[dst[e]], 1);
}

__global__ void k_scan1(const int* __restrict__ counts, int* __restrict__ partial,
                        int* __restrict__ blocksums) {
    __shared__ int sdata[256];
    int base = blockIdx.x * SCAN_CHUNK;
    int t = threadIdx.x;
    int v[4]; int s = 0;
    for (int j = 0; j < 4; j++) {
        int i = base + t * 4 + j;
        v[j] = (i < N_NODES) ? counts[i] : 0;
        s += v[j];
    }
    sdata[t] = s; __syncthreads();
    for (int off = 1; off < 256; off <<= 1) {
        int x = (t >= off) ? sdata[t - off] : 0;
        __syncthreads();
        sdata[t] += x;
        __syncthreads();
    }
    int incl = sdata[t];
    int run = incl - s;
    if (t == 255) blocksums[blockIdx.x] = incl;
    for (int j = 0; j < 4; j++) {
        int i = base + t * 4 + j;
        if (i < N_NODES) partial[i] = run;
        run += v[j];
    }
}

// scan3 with the 98-element block-sum scan folded in (replaces k_scan2)
__global__ void k_scan3(int* __restrict__ row_start, const int* __restrict__ blocksums,
                        int* __restrict__ cursor, const int* __restrict__ counts,
                        float* __restrict__ dis) {
    __shared__ int sd[128], raw[128];
    int t = threadIdx.x;
    if (t < 128) {
        int v = (t < NSCAN_BLK) ? blocksums[t] : 0;
        sd[t] = v; raw[t] = v;
    }
    __syncthreads();
    for (int off = 1; off < 128; off <<= 1) {
        int x = (t < 128 && t >= off) ? sd[t - off] : 0;
        __syncthreads();
        if (t < 128) sd[t] += x;
        __syncthreads();
    }
    int i = blockIdx.x * 256 + t;
    if (i < N_NODES) {
        int j = i >> 10;
        int v = row_start[i] + (sd[j] - raw[j]);
        row_start[i] = v;
        cursor[i] = v;
        dis[i] = rsqrtf(1.0f + (float)counts[i]);
    }
}

// fill packed edge data: {src, coef_bits} — single 8-B store
__global__ void k_fill(const int* __restrict__ src, const int* __restrict__ dst,
                       int* __restrict__ cursor, int2* __restrict__ edata,
                       const float* __restrict__ dis) {
    int e = blockIdx.x * 256 + threadIdx.x;
    if (e < N_EDGES) {
        int d = dst[e], s = src[e];
        int p = atomicAdd(&cursor[d], 1);
        int2 v; v.x = s; v.y = __float_as_int(dis[s] * dis[d]);
        edata[p] = v;
    }
}

// ---------------- fused prep: weight transposes + vecmat + zeroing ----------------
#define PREP_ZBASE (513 + COUTP)
#define PREP_ZN    (N_NODES + 2560 + 2560)
#define PREP_BLOCKS (PREP_ZBASE + (PREP_ZN + 255) / 256)
__global__ void k_prep(const float* __restrict__ W0, const float* __restrict__ W1,
                       const float* __restrict__ W2,
                       u16* __restrict__ T0, u16* __restrict__ T1, u16* __restrict__ T2,
                       const float* __restrict__ vec, float* __restrict__ v20,
                       int* __restrict__ counts, float* __restrict__ statsA,
                       float* __restrict__ statsB) {
    __shared__ float s[256];
    int b = blockIdx.x, t = threadIdx.x;
    if (b < 256) {
        T0[b * 256 + t] = f2b(W0[t * 256 + b]);
    } else if (b < 512) {
        int n = b - 256;
        T1[n * 256 + t] = f2b(W1[t * 256 + n]);
    } else if (b < 512 + COUTP) {
        int n = b - 512;
        T2[n * 256 + t] = f2b(n < COUT ? W2[t * COUT + n] : 0.f);
    } else if (b == 512 + COUTP) {
        s[t] = vec[t];
        __syncthreads();
        float acc = 0.f;
        for (int k = 0; k < 256; k++) acc += s[k] * W0[k * 256 + t];
        v20[t] = acc;
    } else {
        int idx = (b - PREP_ZBASE) * 256 + t;
        if (idx < N_NODES) counts[idx] = 0;
        else if ((idx -= N_NODES) < 2560) statsA[idx] = 0.f;
        else if ((idx -= 2560) < 2560) statsB[idx] = 0.f;
    }
}

// ---------------- GEMM (fp32 A, layer 0): Hout[N,256] = bf16(x) @ W ----------------
// 128x256 tile, 512 threads (8 waves, 2x4 grid of 64x64 sub-tiles).
// B fragments read DIRECTLY from global Wt (L2-resident, layout == fragment
// layout) — no Bs LDS staging, no barrier coupling on B; only As stays in LDS.
__global__ __launch_bounds__(512) void k_gemm_f32a(const float* __restrict__ A,
                                                   const u16* __restrict__ Wt,
                                                   u16* __restrict__ Hout) {
    __shared__ u16 As[128 * 72];
    const int t = threadIdx.x;
    const int wave = t >> 6, lane = t & 63;
    const int lm = lane & 15, quad = lane >> 4;
    const int wr = wave & 1, wc = wave >> 1;
    const int m0 = blockIdx.x * 128;
    const int ar = t >> 2, as_ = (t & 3) * 16;
    const int arow = m0 + ar;
    const u16* bbase = Wt + (wc * 64 + lm) * 256 + quad * 8;
    const f32x4 vz = {0.f, 0.f, 0.f, 0.f};
    f32x4 acc[4][4];
    for (int m = 0; m < 4; m++)
        for (int c = 0; c < 4; c++) acc[m][c] = vz;

    for (int k0 = 0; k0 < 256; k0 += 64) {
        {
            uint4 p0 = {0,0,0,0}, p1 = {0,0,0,0};
            if (arow < N_NODES) {
                const float4* asrc = (const float4*)(A + (size_t)arow * 256 + k0 + as_);
                float4 x0 = asrc[0], x1 = asrc[1], x2 = asrc[2], x3 = asrc[3];
                p0.x = packb(x0.x, x0.y); p0.y = packb(x0.z, x0.w);
                p0.z = packb(x1.x, x1.y); p0.w = packb(x1.z, x1.w);
                p1.x = packb(x2.x, x2.y); p1.y = packb(x2.z, x2.w);
                p1.z = packb(x3.x, x3.y); p1.w = packb(x3.z, x3.w);
            }
            uint4* adst = (uint4*)(As + ar * 72 + as_);
            adst[0] = p0; adst[1] = p1;
        }
        __syncthreads();
#pragma unroll
        for (int kk = 0; kk < 64; kk += 32) {
            s16x8 af[4], bf[4];
#pragma unroll
            for (int m = 0; m < 4; m++)
                af[m] = *(const s16x8*)(As + (wr * 64 + m * 16 + lm) * 72 + kk + quad * 8);
#pragma unroll
            for (int c = 0; c < 4; c++)
                bf[c] = *(const s16x8*)(bbase + c * 16 * 256 + k0 + kk);
#pragma unroll
            for (int c = 0; c < 4; c++)
#pragma unroll
                for (int m = 0; m < 4; m++)
                    acc[m][c] = __builtin_amdgcn_mfma_f32_16x16x32_bf16(af[m], bf[c], acc[m][c], 0, 0, 0);
        }
        __syncthreads();
    }
#pragma unroll
    for (int m = 0; m < 4; m++) {
#pragma unroll
        for (int c = 0; c < 4; c++) {
            int col = wc * 64 + c * 16 + lm;
#pragma unroll
            for (int i = 0; i < 4; i++) {
                int row = m0 + wr * 64 + m * 16 + quad * 4 + i;
                if (row < N_NODES) Hout[(size_t)row * 256 + col] = f2b(acc[m][c][i]);
            }
        }
    }
}

// ---- GEMM with fused BN+ReLU on A + pool: Hout = relu(bn(A)) @ W; pool += colsum ----
__global__ __launch_bounds__(512) void k_gemm_bn(const u16* __restrict__ A,
                                                 const float* __restrict__ stats,
                                                 const float* __restrict__ g,
                                                 const float* __restrict__ bv,
                                                 const u16* __restrict__ Wt,
                                                 u16* __restrict__ Hout,
                                                 float* __restrict__ pool) {
    __shared__ u16 As[128 * 72];
    __shared__ float ggs[256], bcs[256], pls[256];
    const int t = threadIdx.x;
    const int wave = t >> 6, lane = t & 63;
    const int lm = lane & 15, quad = lane >> 4;
    const int wr = wave & 1, wc = wave >> 1;
    const int m0 = blockIdx.x * 128;
    const int ar = t >> 2, as_ = (t & 3) * 16;
    const int arow = m0 + ar;
    const u16* bbase = Wt + (wc * 64 + lm) * 256 + quad * 8;
    if (t < 256) {
        const float inv = 1.0f / (float)N_NODES;
        float mu = stats[t] * inv;
        float var = stats[256 + t] * inv - mu * mu;
        float rs = rsqrtf(var + EPS);
        float gg = g[t] * rs;
        ggs[t] = gg; bcs[t] = bv[t] - mu * gg;
        pls[t] = 0.f;
    }
    __syncthreads();
    const f32x4 vz = {0.f, 0.f, 0.f, 0.f};
    f32x4 acc[4][4];
    for (int m = 0; m < 4; m++)
        for (int c = 0; c < 4; c++) acc[m][c] = vz;

    for (int k0 = 0; k0 < 256; k0 += 64) {
        {
            float f[16];
            if (arow < N_NODES) {
                const uint4* asrc = (const uint4*)(A + (size_t)arow * 256 + k0 + as_);
                uint4 r0 = asrc[0], r1 = asrc[1];
                unpack8(r0, f); unpack8(r1, f + 8);
#pragma unroll
                for (int j = 0; j < 16; j++) {
                    int c = k0 + as_ + j;
                    f[j] = fmaxf(f[j] * ggs[c] + bcs[c], 0.f);
                }
            } else {
#pragma unroll
                for (int j = 0; j < 16; j++) f[j] = 0.f;
            }
            // pool: reduce over lanes with same (lane&3), add to LDS
#pragma unroll
            for (int j = 0; j < 16; j++) {
                float v = f[j];
                v += __shfl_xor(v, 4);  v += __shfl_xor(v, 8);
                v += __shfl_xor(v, 16); v += __shfl_xor(v, 32);
                if (lane < 4) atomicAdd(&pls[k0 + lane * 16 + j], v);
            }
            uint4 p0, p1;
            p0.x = packb(f[0], f[1]);   p0.y = packb(f[2], f[3]);
            p0.z = packb(f[4], f[5]);   p0.w = packb(f[6], f[7]);
            p1.x = packb(f[8], f[9]);   p1.y = packb(f[10], f[11]);
            p1.z = packb(f[12], f[13]); p1.w = packb(f[14], f[15]);
            uint4* adst = (uint4*)(As + ar * 72 + as_);
            adst[0] = p0; adst[1] = p1;
        }
        __syncthreads();
#pragma unroll
        for (int kk = 0; kk < 64; kk += 32) {
            s16x8 af[4], bf[4];
#pragma unroll
            for (int m = 0; m < 4; m++)
                af[m] = *(const s16x8*)(As + (wr * 64 + m * 16 + lm) * 72 + kk + quad * 8);
#pragma unroll
            for (int c = 0; c < 4; c++)
                bf[c] = *(const s16x8*)(bbase + c * 16 * 256 + k0 + kk);
#pragma unroll
            for (int c = 0; c < 4; c++)
#pragma unroll
                for (int m = 0; m < 4; m++)
                    acc[m][c] = __builtin_amdgcn_mfma_f32_16x16x32_bf16(af[m], bf[c], acc[m][c], 0, 0, 0);
        }
        __syncthreads();
    }
    if (t < 256) atomicAdd(&pool[(blockIdx.x & 7) * 256 + t], pls[t]);
#pragma unroll
    for (int m = 0; m < 4; m++) {
#pragma unroll
        for (int c = 0; c < 4; c++) {
            int col = wc * 64 + c * 16 + lm;
#pragma unroll
            for (int i = 0; i < 4; i++) {
                int row = m0 + wr * 64 + m * 16 + quad * 4 + i;
                if (row < N_NODES) Hout[(size_t)row * 256 + col] = f2b(acc[m][c][i]);
            }
        }
    }
}

// ---- GEMM layer 2 with fused BN+ReLU + pool: Hout[N,64] = relu(bn(A)) @ W2pad ----
__global__ __launch_bounds__(512) void k_gemm2_bn(const u16* __restrict__ A,
                                                  const float* __restrict__ stats,
                                                  const float* __restrict__ g,
                                                  const float* __restrict__ bv,
                                                  const u16* __restrict__ Wt,
                                                  u16* __restrict__ Hout,
                                                  float* __restrict__ pool) {
    __shared__ u16 As[128 * 72];
    __shared__ float ggs[256], bcs[256], pls[256];
    const int t = threadIdx.x;
    const int wave = t >> 6, lane = t & 63;
    const int lm = lane & 15, quad = lane >> 4;
    const int m0 = blockIdx.x * 128;
    const int ar = t >> 2, as_ = (t & 3) * 16;
    const int arow = m0 + ar;
    const u16* bbase = Wt + lm * 256 + quad * 8;
    if (t < 256) {
        const float inv = 1.0f / (float)N_NODES;
        float mu = stats[t] * inv;
        float var = stats[256 + t] * inv - mu * mu;
        float rs = rsqrtf(var + EPS);
        float gg = g[t] * rs;
        ggs[t] = gg; bcs[t] = bv[t] - mu * gg;
        pls[t] = 0.f;
    }
    __syncthreads();
    const f32x4 vz = {0.f, 0.f, 0.f, 0.f};
    f32x4 acc[4]; acc[0] = vz; acc[1] = vz; acc[2] = vz; acc[3] = vz;

    for (int k0 = 0; k0 < 256; k0 += 64) {
        {
            float f[16];
            if (arow < N_NODES) {
                const uint4* asrc = (const uint4*)(A + (size_t)arow * 256 + k0 + as_);
                uint4 r0 = asrc[0], r1 = asrc[1];
                unpack8(r0, f); unpack8(r1, f + 8);
#pragma unroll
                for (int j = 0; j < 16; j++) {
                    int c = k0 + as_ + j;
                    f[j] = fmaxf(f[j] * ggs[c] + bcs[c], 0.f);
                }
            } else {
#pragma unroll
                for (int j = 0; j < 16; j++) f[j] = 0.f;
            }
#pragma unroll
            for (int j = 0; j < 16; j++) {
                float v = f[j];
                v += __shfl_xor(v, 4);  v += __shfl_xor(v, 8);
                v += __shfl_xor(v, 16); v += __shfl_xor(v, 32);
                if (lane < 4) atomicAdd(&pls[k0 + lane * 16 + j], v);
            }
            uint4 p0, p1;
            p0.x = packb(f[0], f[1]);   p0.y = packb(f[2], f[3]);
            p0.z = packb(f[4], f[5]);   p0.w = packb(f[6], f[7]);
            p1.x = packb(f[8], f[9]);   p1.y = packb(f[10], f[11]);
            p1.z = packb(f[12], f[13]); p1.w = packb(f[14], f[15]);
            uint4* adst = (uint4*)(As + ar * 72 + as_);
            adst[0] = p0; adst[1] = p1;
        }
        __syncthreads();
#pragma unroll
        for (int kk = 0; kk < 64; kk += 32) {
            s16x8 af = *(const s16x8*)(As + (wave * 16 + lm) * 72 + kk + quad * 8);
#pragma unroll
            for (int c = 0; c < 4; c++) {
                s16x8 bf = *(const s16x8*)(bbase + c * 16 * 256 + k0 + kk);
                acc[c] = __builtin_amdgcn_mfma_f32_16x16x32_bf16(af, bf, acc[c], 0, 0, 0);
            }
        }
        __syncthreads();
    }
    if (t < 256) atomicAdd(&pool[(blockIdx.x & 7) * 256 + t], pls[t]);
#pragma unroll
    for (int c = 0; c < 4; c++) {
        int col = c * 16 + lm;
#pragma unroll
        for (int i = 0; i < 4; i++) {
            int row = m0 + wave * 16 + quad * 4 + i;
            if (row < N_NODES) Hout[(size_t)row * COUTP + col] = f2b(acc[c][i]);
        }
    }
}

// ---- aggregation L0/L1: at the random-gather memory-system wall; unchanged ----
__global__ __launch_bounds__(256) void k_agg(const u16* __restrict__ H2,
                                             const int* __restrict__ row_start,
                                             const int* __restrict__ counts,
                                             const int2* __restrict__ edata,
                                             const float* __restrict__ dis,
                                             const float* __restrict__ bias,
                                             const float* __restrict__ v2,
                                             u16* __restrict__ OutB,
                                             float* __restrict__ stats) {
    __shared__ float ls[512];
    const int t = threadIdx.x, wave = t >> 6, lane = t & 63;
    const int half = lane >> 5, hl = lane & 31;
    const int ci = hl * 8;
    const float4 bbA = *(const float4*)(bias + ci);
    const float4 bbB = *(const float4*)(bias + ci + 4);
    const float4 vvA = *(const float4*)(v2 + ci);
    const float4 vvB = *(const float4*)(v2 + ci + 4);
    float s[8], q[8];
#pragma unroll
    for (int j = 0; j < 8; j++) { s[j] = 0.f; q[j] = 0.f; }

    const int gwave = blockIdx.x * 4 + wave;      // 0..8191
    const int nid = gwave + lane * AGG_WAVES;
    const bool nv = (lane < AGG_NPW) && (nid < N_NODES);
    const int   my_rs = nv ? row_start[nid] : 0;
    const int   my_ct = nv ? counts[nid] : 0;
    const float my_dn = nv ? dis[nid] : 0.f;

    int beg = __shfl(my_rs, 0), cnt = __shfl(my_ct, 0);
    int2 my_e = {0, 0};
    if (lane < cnt) my_e = edata[beg + lane];

    for (int i = 0; i < AGG_NPW; i++) {
        const int node = gwave + i * AGG_WAVES;
        if (node >= N_NODES) break;
        const int2 cur_e = my_e;
        const int  ccnt = cnt, cbeg = beg;
        const float dn = __shfl(my_dn, i);
        const uint4 rs_ = *(const uint4*)(H2 + (size_t)node * 256 + ci);
        if (i + 1 < AGG_NPW && node + AGG_WAVES < N_NODES) {
            beg = __shfl(my_rs, i + 1);
            cnt = __shfl(my_ct, i + 1);
            int2 tmp = {0, 0};
            if (lane < cnt) tmp = edata[beg + lane];
            my_e = tmp;
        }
        const int cnt64 = ccnt < 64 ? ccnt : 64;
        const int cnt8 = (cnt64 + 7) & ~7;
        float a[8];
#pragma unroll
        for (int j = 0; j < 8; j++) a[j] = 0.f;
        float cs = 0.f;
        for (int e = 0; e < cnt8; e += 8) {
            const int   si0 = __shfl(cur_e.x, e + half);
            const int   si1 = __shfl(cur_e.x, e + 2 + half);
            const int   si2 = __shfl(cur_e.x, e + 4 + half);
            const int   si3 = __shfl(cur_e.x, e + 6 + half);
            const float cf0 = __int_as_float(__shfl(cur_e.y, e + half));
            const float cf1 = __int_as_float(__shfl(cur_e.y, e + 2 + half));
            const float cf2 = __int_as_float(__shfl(cur_e.y, e + 4 + half));
            const float cf3 = __int_as_float(__shfl(cur_e.y, e + 6 + half));
            const uint4 r0 = *(const uint4*)(H2 + (size_t)si0 * 256 + ci);
            const uint4 r1 = *(const uint4*)(H2 + (size_t)si1 * 256 + ci);
            const uint4 r2 = *(const uint4*)(H2 + (size_t)si2 * 256 + ci);
            const uint4 r3 = *(const uint4*)(H2 + (size_t)si3 * 256 + ci);
            cs += cf0 + cf1 + cf2 + cf3;
            a[0] += cf0*b2f(r0.x&0xffffu) + cf1*b2f(r1.x&0xffffu) + cf2*b2f(r2.x&0xffffu) + cf3*b2f(r3.x&0xffffu);
            a[1] += cf0*b2f(r0.x>>16)     + cf1*b2f(r1.x>>16)     + cf2*b2f(r2.x>>16)     + cf3*b2f(r3.x>>16);
            a[2] += cf0*b2f(r0.y&0xffffu) + cf1*b2f(r1.y&0xffffu) + cf2*b2f(r2.y&0xffffu) + cf3*b2f(r3.y&0xffffu);
            a[3] += cf0*b2f(r0.y>>16)     + cf1*b2f(r1.y>>16)     + cf2*b2f(r2.y>>16)     + cf3*b2f(r3.y>>16);
            a[4] += cf0*b2f(r0.z&0xffffu) + cf1*b2f(r1.z&0xffffu) + cf2*b2f(r2.z&0xffffu) + cf3*b2f(r3.z&0xffffu);
            a[5] += cf0*b2f(r0.z>>16)     + cf1*b2f(r1.z>>16)     + cf2*b2f(r2.z>>16)     + cf3*b2f(r3.z>>16);
            a[6] += cf0*b2f(r0.w&0xffffu) + cf1*b2f(r1.w&0xffffu) + cf2*b2f(r2.w&0xffffu) + cf3*b2f(r3.w&0xffffu);
            a[7] += cf0*b2f(r0.w>>16)     + cf1*b2f(r1.w>>16)     + cf2*b2f(r2.w>>16)     + cf3*b2f(r3.w>>16);
        }
        if (ccnt > 64) {
            int e2 = 64;
            for (; e2 + 2 <= ccnt; e2 += 2) {
                const int2 ed_ = edata[cbeg + e2 + half];
                const float cf = __int_as_float(ed_.y);
                const uint4 r = *(const uint4*)(H2 + (size_t)ed_.x * 256 + ci);
                cs += cf;
                a[0] += cf*b2f(r.x&0xffffu); a[1] += cf*b2f(r.x>>16);
                a[2] += cf*b2f(r.y&0xffffu); a[3] += cf*b2f(r.y>>16);
                a[4] += cf*b2f(r.z&0xffffu); a[5] += cf*b2f(r.z>>16);
                a[6] += cf*b2f(r.w&0xffffu); a[7] += cf*b2f(r.w>>16);
            }
            if (e2 < ccnt && half == 0) {
                const int2 ed_ = edata[cbeg + e2];
                const float cf = __int_as_float(ed_.y);
                const uint4 r = *(const uint4*)(H2 + (size_t)ed_.x * 256 + ci);
                cs += cf;
                a[0] += cf*b2f(r.x&0xffffu); a[1] += cf*b2f(r.x>>16);
                a[2] += cf*b2f(r.y&0xffffu); a[3] += cf*b2f(r.y>>16);
                a[4] += cf*b2f(r.z&0xffffu); a[5] += cf*b2f(r.z>>16);
                a[6] += cf*b2f(r.w&0xffffu); a[7] += cf*b2f(r.w>>16);
            }
        }
        cs += __shfl_xor(cs, 32);
#pragma unroll
        for (int j = 0; j < 8; j++) a[j] += __shfl_xor(a[j], 32);
        const float sc = dn * dn, cv = cs + sc;
        const float f0 = a[0] + sc*b2f(rs_.x&0xffffu) + cv*vvA.x + bbA.x;
        const float f1 = a[1] + sc*b2f(rs_.x>>16)     + cv*vvA.y + bbA.y;
        const float f2 = a[2] + sc*b2f(rs_.y&0xffffu) + cv*vvA.z + bbA.z;
        const float f3 = a[3] + sc*b2f(rs_.y>>16)     + cv*vvA.w + bbA.w;
        const float f4 = a[4] + sc*b2f(rs_.z&0xffffu) + cv*vvB.x + bbB.x;
        const float f5 = a[5] + sc*b2f(rs_.z>>16)     + cv*vvB.y + bbB.y;
        const float f6 = a[6] + sc*b2f(rs_.w&0xffffu) + cv*vvB.z + bbB.z;
        const float f7 = a[7] + sc*b2f(rs_.w>>16)     + cv*vvB.w + bbB.w;
        if (half == 0) {
            uint4 o;
            o.x = packb(f0, f1); o.y = packb(f2, f3);
            o.z = packb(f4, f5); o.w = packb(f6, f7);
            *(uint4*)(OutB + (size_t)node * 256 + ci) = o;
        }
        s[0] += f0; q[0] += f0*f0;  s[1] += f1; q[1] += f1*f1;
        s[2] += f2; q[2] += f2*f2;  s[3] += f3; q[3] += f3*f3;
        s[4] += f4; q[4] += f4*f4;  s[5] += f5; q[5] += f5*f5;
        s[6] += f6; q[6] += f6*f6;  s[7] += f7; q[7] += f7*f7;
    }
    ls[t] = 0.f; ls[256 + t] = 0.f;
    __syncthreads();
    if (half == 0) {
#pragma unroll
        for (int j = 0; j < 8; j++) {
            atomicAdd(&ls[ci + j], s[j]);
            atomicAdd(&ls[256 + ci + j], q[j]);
        }
    }
    __syncthreads();
    atomicAdd(&stats[t], ls[t]);
    atomicAdd(&stats[256 + t], ls[256 + t]);
}

// ---------------- virtual node update + v2_next = vx_new @ Wnext ----------------
__global__ void k_vx(const float* __restrict__ pool, const float* __restrict__ vx_old,
                     const float* __restrict__ vnW, const float* __restrict__ vnb,
                     const float* __restrict__ lng, const float* __restrict__ lnb,
                     float* __restrict__ vx_new,
                     const float* __restrict__ Wnext, int ncn, int npn,
                     float* __restrict__ v2n) {
    __shared__ float s[256];
    __shared__ float red[256];
    int t = threadIdx.x;
    float pv = 0.f;
#pragma unroll
    for (int r = 0; r < 8; r++) pv += pool[r * 256 + t];
    s[t] = pv + vx_old[t];
    __syncthreads();
    float y = vnb[t];
    for (int k = 0; k < 256; k++) y += s[k] * vnW[k * 256 + t];
    red[t] = y; __syncthreads();
    for (int off = 128; off > 0; off >>= 1) {
        if (t < off) red[t] += red[t + off];
        __syncthreads();
    }
    float mu = red[0] * (1.f / 256.f);
    __syncthreads();
    float d = y - mu;
    red[t] = d * d; __syncthreads();
    for (int off = 128; off > 0; off >>= 1) {
        if (t < off) red[t] += red[t + off];
        __syncthreads();
    }
    float var = red[0] * (1.f / 256.f);
    float v = fmaxf(d * rsqrtf(var + EPS) * lng[t] + lnb[t], 0.f);
    vx_new[t] = v;
    __syncthreads();
    s[t] = v;
    __syncthreads();
    float acc = 0.f;
    if (t < ncn) {
        for (int k = 0; k < 256; k++) acc += s[k] * Wnext[k * ncn + t];
    }
    if (t < npn) v2n[t] = acc;
}

// ---- layer-2 aggregation + (cs+dn^2)*v2 fold + log_softmax ----
// COUTP=64: each gathered row is exactly one 128-B cache line.
__global__ __launch_bounds__(256) void k_agg2(const u16* __restrict__ H2,
                                              const int* __restrict__ row_start,
                                              const int* __restrict__ counts,
                                              const int2* __restrict__ edata,
                                              const float* __restrict__ dis,
                                              const float* __restrict__ bias,
                                              const float* __restrict__ v2,
                                              float* __restrict__ OutF) {
    const int t = threadIdx.x, wave = t >> 6, lane = t & 63;
    const int half = lane >> 5, hl = lane & 31;
    const bool cact = hl < 20;
    const int c0 = 2 * hl;
    float bb0 = 0.f, bb1 = 0.f, vv0 = 0.f, vv1 = 0.f;
    if (cact) {
        float2 bv = *(const float2*)(bias + c0); bb0 = bv.x; bb1 = bv.y;
        float2 vvv = *(const float2*)(v2 + c0);  vv0 = vvv.x; vv1 = vvv.y;
    }
    const int nbase = blockIdx.x * 16 + wave * 4;
    for (int i = 0; i < 4; i++) {
        const int node = nbase + i;
        const int beg = row_start[node], cnt = counts[node];
        const float dn = dis[node];
        float a0 = 0.f, a1 = 0.f, cs = 0.f;
        int e = half;
        for (; e + 6 < cnt; e += 8) {
            int2 ea = edata[beg+e],   eb = edata[beg+e+2];
            int2 ec = edata[beg+e+4], ed = edata[beg+e+6];
            float ca = __int_as_float(ea.y), cb = __int_as_float(eb.y);
            float cc = __int_as_float(ec.y), cd = __int_as_float(ed.y);
            u32 ra = 0, rb = 0, rc = 0, rd = 0;
            if (cact) {
                ra = *(const u32*)(H2 + (size_t)ea.x * COUTP + c0);
                rb = *(const u32*)(H2 + (size_t)eb.x * COUTP + c0);
                rc = *(const u32*)(H2 + (size_t)ec.x * COUTP + c0);
                rd = *(const u32*)(H2 + (size_t)ed.x * COUTP + c0);
            }
            cs += ca + cb + cc + cd;
            a0 += ca*b2f(ra&0xffffu) + cb*b2f(rb&0xffffu) + cc*b2f(rc&0xffffu) + cd*b2f(rd&0xffffu);
            a1 += ca*b2f(ra>>16)     + cb*b2f(rb>>16)     + cc*b2f(rc>>16)     + cd*b2f(rd>>16);
        }
        for (; e < cnt; e += 2) {
            int2 ea = edata[beg+e];
            float ca = __int_as_float(ea.y);
            u32 ra = cact ? *(const u32*)(H2 + (size_t)ea.x * COUTP + c0) : 0u;
            cs += ca;
            a0 += ca*b2f(ra&0xffffu); a1 += ca*b2f(ra>>16);
        }
        a0 += __shfl_xor(a0, 32);
        a1 += __shfl_xor(a1, 32);
        cs += __shfl_xor(cs, 32);
        const float sc = dn * dn;
        u32 rs_ = cact ? *(const u32*)(H2 + (size_t)node * COUTP + c0) : 0u;
        float h0 = a0 + sc*b2f(rs_&0xffffu) + (cs+sc)*vv0 + bb0;
        float h1 = a1 + sc*b2f(rs_>>16)     + (cs+sc)*vv1 + bb1;
        float m = cact ? fmaxf(h0, h1) : -3.0e38f;
#pragma unroll
        for (int off = 16; off > 0; off >>= 1) m = fmaxf(m, __shfl_xor(m, off));
        float ex = cact ? (expf(h0 - m) + expf(h1 - m)) : 0.f;
        float se = ex;
#pragma unroll
        for (int off = 16; off > 0; off >>= 1) se += __shfl_xor(se, off);
        float lg = logf(se);
        if (cact && half == 0) {
            float2 o = {h0 - m - lg, h1 - m - lg};
            *(float2*)(OutF + (size_t)node * COUT + c0) = o;
        }
    }
}

extern "C" void kernel_launch(void* const* d_in, const int* in_sizes, int n_in,
                              void* d_out, int out_size, void* d_ws, size_t ws_size,
                              hipStream_t stream) {
    const float* x   = (const float*)d_in[0];
    const int*   ei  = (const int*)d_in[1];
    const int*   esrc = ei;
    const int*   edst = ei + N_EDGES;
    const float* W0 = (const float*)d_in[2];  const float* b0 = (const float*)d_in[3];
    const float* W1 = (const float*)d_in[4];  const float* b1 = (const float*)d_in[5];
    const float* W2 = (const float*)d_in[6];  const float* b2 = (const float*)d_in[7];
    const float* bg0 = (const float*)d_in[8]; const float* bb0 = (const float*)d_in[9];
    const float* bg1 = (const float*)d_in[10]; const float* bb1 = (const float*)d_in[11];
    const float* vn_emb = (const float*)d_in[12];
    const float* vW0 = (const float*)d_in[13]; const float* vb0 = (const float*)d_in[14];
    const float* lg0 = (const float*)d_in[15]; const float* lb0 = (const float*)d_in[16];
    const float* vW1 = (const float*)d_in[17]; const float* vb1 = (const float*)d_in[18];
    const float* lg1 = (const float*)d_in[19]; const float* lb1 = (const float*)d_in[20];

    char* w = (char*)d_ws;
    auto alloc = [&](size_t bytes) { void* p = (void*)w; w += ((bytes + 255) / 256) * 256; return p; };
    u16* H2    = (u16*)alloc((size_t)N_NODES * 256 * 2);
    u16* OutB  = (u16*)alloc((size_t)N_NODES * 256 * 2);
    int2* edata = (int2*)alloc((size_t)N_EDGES * 8);
    int* counts = (int*)alloc((size_t)N_NODES * 4);
    int* rowst  = (int*)alloc((size_t)N_NODES * 4);
    int* cursor = (int*)alloc((size_t)N_NODES * 4);
    float* dis  = (float*)alloc((size_t)N_NODES * 4);
    u16* Wtb0 = (u16*)alloc(256 * 256 * 2);
    u16* Wtb1 = (u16*)alloc(256 * 256 * 2);
    u16* Wt2b = (u16*)alloc(COUTP * 256 * 2);
    int* scanblk = (int*)alloc(128 * 4);
    float* statsA = (float*)alloc(2560 * 4);   // sum[256], sq[256], pool[8*256]
    float* statsB = (float*)alloc(2560 * 4);
    float* vxA = (float*)alloc(256 * 4);
    float* vxB = (float*)alloc(256 * 4);
    float* v20 = (float*)alloc(256 * 4);
    float* v21 = (float*)alloc(256 * 4);
    float* v22 = (float*)alloc(COUTP * 4);
    (void)ws_size; (void)in_sizes; (void)n_in; (void)out_size;

    // ---- fused prep: transposes + vecmat + zeroing ----
    k_prep<<<PREP_BLOCKS, 256, 0, stream>>>(W0, W1, W2, Wtb0, Wtb1, Wt2b,
                                            vn_emb, v20, counts, statsA, statsB);
    // ---- graph prep: degrees + CSR + packed edge data ----
    k_count<<<(N_EDGES + 255) / 256, 256, 0, stream>>>(edst, counts);
    k_scan1<<<NSCAN_BLK, 256, 0, stream>>>(counts, rowst, scanblk);
    k_scan3<<<(N_NODES + 255) / 256, 256, 0, stream>>>(rowst, scanblk, cursor, counts, dis);
    k_fill<<<(N_EDGES + 255) / 256, 256, 0, stream>>>(esrc, edst, cursor, edata, dis);

    const int gemmblk = (N_NODES + 127) / 128;

    // ---- layer 0 ----
    k_gemm_f32a<<<gemmblk, 512, 0, stream>>>(x, Wtb0, H2);
    k_agg<<<AGG_BLOCKS, 256, 0, stream>>>(H2, rowst, counts, edata, dis, b0, v20, OutB, statsA);
    // ---- layer 1 (BN0+ReLU+pool fused into gemm A-staging) ----
    k_gemm_bn<<<gemmblk, 512, 0, stream>>>(OutB, statsA, bg0, bb0, Wtb1, H2, statsA + 512);
    k_vx<<<1, 256, 0, stream>>>(statsA + 512, vn_emb, vW0, vb0, lg0, lb0, vxA, W1, 256, 256, v21);
    k_agg<<<AGG_BLOCKS, 256, 0, stream>>>(H2, rowst, counts, edata, dis, b1, v21, OutB, statsB);
    // ---- layer 2 ----
    k_gemm2_bn<<<gemmblk, 512, 0, stream>>>(OutB, statsB, bg1, bb1, Wt2b, H2, statsB + 512);
    k_vx<<<1, 256, 0, stream>>>(statsB + 512, vxA, vW1, vb1, lg1, lb1, vxB, W2, COUT, COUTP, v22);
    k_agg2<<<N_NODES / 16, 256, 0, stream>>>(H2, rowst, counts, edata, dis, b2, v22, (float*)d_out);
}

// Round 7
// 738.355 us; speedup vs baseline: 1.0066x; 1.0066x over previous
//
#include <hip/hip_runtime.h>
#include <hip/hip_bf16.h>
#include <cstdint>

#define N_NODES 100000
#define N_EDGES 800000
#define CH      256
#define COUT    40
#define COUTP   64   // padded out-channels; 128B = one cache line per row
#define EPS     1e-5f
#define SCAN_CHUNK 1024
#define NSCAN_BLK  98   // ceil(100000/1024)
#define AGG_NPW 16      // nodes per wave in k_agg (strided)
#define AGG_BLOCKS 2048 // full residency: 8 blocks/CU * 256 CU
#define AGG_WAVES  (AGG_BLOCKS * 4)   // 8192 waves; stride for node assignment

typedef unsigned short u16;
typedef unsigned int   u32;
typedef short s16x8 __attribute__((ext_vector_type(8)));
typedef float f32x4 __attribute__((ext_vector_type(4)));

__device__ __forceinline__ float b2f(u32 u) { return __uint_as_float(u << 16); }
__device__ __forceinline__ u16 f2b(float f) {
    u32 u = __float_as_uint(f);
    u32 r = (u + 0x7fffu + ((u >> 16) & 1u)) >> 16;   // RNE
    return (u16)r;
}
__device__ __forceinline__ u32 packb(float a, float b) {
    return (u32)f2b(a) | ((u32)f2b(b) << 16);
}
__device__ __forceinline__ void unpack8(uint4 v, float* f) {
    f[0] = b2f(v.x & 0xffffu); f[1] = b2f(v.x >> 16);
    f[2] = b2f(v.y & 0xffffu); f[3] = b2f(v.y >> 16);
    f[4] = b2f(v.z & 0xffffu); f[5] = b2f(v.z >> 16);
    f[6] = b2f(v.w & 0xffffu); f[7] = b2f(v.w >> 16);
}

// ---------------- CSR build ----------------
__global__ void k_count(const int* __restrict__ dst, int* __restrict__ counts) {
    int e = blockIdx.x * 256 + threadIdx.x;
    if (e < N_EDGES) atomicAdd(&counts[dst[e]], 1);
}

__global__ void k_scan1(const int* __restrict__ counts, int* __restrict__ partial,
                        int* __restrict__ blocksums) {
    __shared__ int sdata[256];
    int base = blockIdx.x * SCAN_CHUNK;
    int t = threadIdx.x;
    int v[4]; int s = 0;
    for (int j = 0; j < 4; j++) {
        int i = base + t * 4 + j;
        v[j] = (i < N_NODES) ? counts[i] : 0;
        s += v[j];
    }
    sdata[t] = s; __syncthreads();
    for (int off = 1; off < 256; off <<= 1) {
        int x = (t >= off) ? sdata[t - off] : 0;
        __syncthreads();
        sdata[t] += x;
        __syncthreads();
    }
    int incl = sdata[t];
    int run = incl - s;
    if (t == 255) blocksums[blockIdx.x] = incl;
    for (int j = 0; j < 4; j++) {
        int i = base + t * 4 + j;
        if (i < N_NODES) partial[i] = run;
        run += v[j];
    }
}

// scan3 with the 98-element block-sum scan folded in (replaces k_scan2)
__global__ void k_scan3(int* __restrict__ row_start, const int* __restrict__ blocksums,
                        int* __restrict__ cursor, const int* __restrict__ counts,
                        float* __restrict__ dis) {
    __shared__ int sd[128], raw[128];
    int t = threadIdx.x;
    if (t < 128) {
        int v = (t < NSCAN_BLK) ? blocksums[t] : 0;
        sd[t] = v; raw[t] = v;
    }
    __syncthreads();
    for (int off = 1; off < 128; off <<= 1) {
        int x = (t < 128 && t >= off) ? sd[t - off] : 0;
        __syncthreads();
        if (t < 128) sd[t] += x;
        __syncthreads();
    }
    int i = blockIdx.x * 256 + t;
    if (i < N_NODES) {
        int j = i >> 10;
        int v = row_start[i] + (sd[j] - raw[j]);
        row_start[i] = v;
        cursor[i] = v;
        dis[i] = rsqrtf(1.0f + (float)counts[i]);
    }
}

// fill packed edge data: {src, coef_bits} — nontemporal 8-B store (random scatter;
// avoid write-allocate of ~100MB of lines that k_agg will stream anyway)
__global__ void k_fill(const int* __restrict__ src, const int* __restrict__ dst,
                       int* __restrict__ cursor, int2* __restrict__ edata,
                       const float* __restrict__ dis) {
    int e = blockIdx.x * 256 + threadIdx.x;
    if (e < N_EDGES) {
        int d = dst[e], s = src[e];
        int p = atomicAdd(&cursor[d], 1);
        unsigned long long payload = (unsigned long long)(u32)s |
            ((unsigned long long)(u32)__float_as_uint(dis[s] * dis[d]) << 32);
        __builtin_nontemporal_store(payload, (unsigned long long*)&edata[p]);
    }
}

// ---------------- fused prep: weight transposes + vecmat + zeroing ----------------
#define PREP_ZBASE (513 + COUTP)
#define PREP_ZN    (N_NODES + 2560 + 2560)
#define PREP_BLOCKS (PREP_ZBASE + (PREP_ZN + 255) / 256)
__global__ void k_prep(const float* __restrict__ W0, const float* __restrict__ W1,
                       const float* __restrict__ W2,
                       u16* __restrict__ T0, u16* __restrict__ T1, u16* __restrict__ T2,
                       const float* __restrict__ vec, float* __restrict__ v20,
                       int* __restrict__ counts, float* __restrict__ statsA,
                       float* __restrict__ statsB) {
    __shared__ float s[256];
    int b = blockIdx.x, t = threadIdx.x;
    if (b < 256) {
        T0[b * 256 + t] = f2b(W0[t * 256 + b]);
    } else if (b < 512) {
        int n = b - 256;
        T1[n * 256 + t] = f2b(W1[t * 256 + n]);
    } else if (b < 512 + COUTP) {
        int n = b - 512;
        T2[n * 256 + t] = f2b(n < COUT ? W2[t * COUT + n] : 0.f);
    } else if (b == 512 + COUTP) {
        s[t] = vec[t];
        __syncthreads();
        float acc = 0.f;
        for (int k = 0; k < 256; k++) acc += s[k] * W0[k * 256 + t];
        v20[t] = acc;
    } else {
        int idx = (b - PREP_ZBASE) * 256 + t;
        if (idx < N_NODES) counts[idx] = 0;
        else if ((idx -= N_NODES) < 2560) statsA[idx] = 0.f;
        else if ((idx -= 2560) < 2560) statsB[idx] = 0.f;
    }
}

// ---------------- GEMM (fp32 A, layer 0): Hout[N,256] = bf16(x) @ W ----------------
// 128x256 tile, 512 threads. Software-pipelined: next k0's A loads issued into
// registers before the barrier, hidden under the MFMA phase. B staged in LDS per k0.
__global__ __launch_bounds__(512) void k_gemm_f32a(const float* __restrict__ A,
                                                   const u16* __restrict__ Wt,
                                                   u16* __restrict__ Hout) {
    __shared__ u16 Bs[256 * 72];
    __shared__ u16 As[128 * 72];
    const int t = threadIdx.x;
    const int wave = t >> 6, lane = t & 63;
    const int lm = lane & 15, quad = lane >> 4;
    const int wr = wave & 1, wc = wave >> 1;
    const int m0 = blockIdx.x * 128;
    const int ar = t >> 2, as_ = (t & 3) * 16;
    const int arow = m0 + ar;
    const int brow = t >> 1, bo = (t & 1) * 32;
    const f32x4 vz = {0.f, 0.f, 0.f, 0.f};
    f32x4 acc[4][4];
    for (int m = 0; m < 4; m++)
        for (int c = 0; c < 4; c++) acc[m][c] = vz;

    // prologue: prefetch A tile for k0=0
    float4 xa0 = {0,0,0,0}, xa1 = xa0, xa2 = xa0, xa3 = xa0;
    if (arow < N_NODES) {
        const float4* asrc = (const float4*)(A + (size_t)arow * 256 + as_);
        xa0 = asrc[0]; xa1 = asrc[1]; xa2 = asrc[2]; xa3 = asrc[3];
    }

    for (int k0 = 0; k0 < 256; k0 += 64) {
        {
            // B stage (L2-hot)
            const uint4* bsrc = (const uint4*)(Wt + brow * 256 + k0 + bo);
            uint4* bdst = (uint4*)(Bs + brow * 72 + bo);
#pragma unroll
            for (int j = 0; j < 4; j++) bdst[j] = bsrc[j];
            // A pack from prefetched regs
            uint4 p0 = {0,0,0,0}, p1 = {0,0,0,0};
            if (arow < N_NODES) {
                p0.x = packb(xa0.x, xa0.y); p0.y = packb(xa0.z, xa0.w);
                p0.z = packb(xa1.x, xa1.y); p0.w = packb(xa1.z, xa1.w);
                p1.x = packb(xa2.x, xa2.y); p1.y = packb(xa2.z, xa2.w);
                p1.z = packb(xa3.x, xa3.y); p1.w = packb(xa3.z, xa3.w);
            }
            uint4* adst = (uint4*)(As + ar * 72 + as_);
            adst[0] = p0; adst[1] = p1;
            // prefetch next k0's A (latency hides under MFMA phase)
            if (k0 + 64 < 256 && arow < N_NODES) {
                const float4* anext = (const float4*)(A + (size_t)arow * 256 + k0 + 64 + as_);
                xa0 = anext[0]; xa1 = anext[1]; xa2 = anext[2]; xa3 = anext[3];
            }
        }
        __syncthreads();
#pragma unroll
        for (int kk = 0; kk < 64; kk += 32) {
            s16x8 af[4], bf[4];
#pragma unroll
            for (int m = 0; m < 4; m++)
                af[m] = *(const s16x8*)(As + (wr * 64 + m * 16 + lm) * 72 + kk + quad * 8);
#pragma unroll
            for (int c = 0; c < 4; c++)
                bf[c] = *(const s16x8*)(Bs + (wc * 64 + c * 16 + lm) * 72 + kk + quad * 8);
#pragma unroll
            for (int c = 0; c < 4; c++)
#pragma unroll
                for (int m = 0; m < 4; m++)
                    acc[m][c] = __builtin_amdgcn_mfma_f32_16x16x32_bf16(af[m], bf[c], acc[m][c], 0, 0, 0);
        }
        __syncthreads();
    }
#pragma unroll
    for (int m = 0; m < 4; m++) {
#pragma unroll
        for (int c = 0; c < 4; c++) {
            int col = wc * 64 + c * 16 + lm;
#pragma unroll
            for (int i = 0; i < 4; i++) {
                int row = m0 + wr * 64 + m * 16 + quad * 4 + i;
                if (row < N_NODES) Hout[(size_t)row * 256 + col] = f2b(acc[m][c][i]);
            }
        }
    }
}

// ---- GEMM with fused BN+ReLU on A + pool: Hout = relu(bn(A)) @ W; pool += colsum ----
__global__ __launch_bounds__(512) void k_gemm_bn(const u16* __restrict__ A,
                                                 const float* __restrict__ stats,
                                                 const float* __restrict__ g,
                                                 const float* __restrict__ bv,
                                                 const u16* __restrict__ Wt,
                                                 u16* __restrict__ Hout,
                                                 float* __restrict__ pool) {
    __shared__ u16 Bs[256 * 72];
    __shared__ u16 As[128 * 72];
    __shared__ float ggs[256], bcs[256], pls[256];
    const int t = threadIdx.x;
    const int wave = t >> 6, lane = t & 63;
    const int lm = lane & 15, quad = lane >> 4;
    const int wr = wave & 1, wc = wave >> 1;
    const int m0 = blockIdx.x * 128;
    const int ar = t >> 2, as_ = (t & 3) * 16;
    const int arow = m0 + ar;
    const int brow = t >> 1, bo = (t & 1) * 32;
    if (t < 256) {
        const float inv = 1.0f / (float)N_NODES;
        float mu = stats[t] * inv;
        float var = stats[256 + t] * inv - mu * mu;
        float rs = rsqrtf(var + EPS);
        float gg = g[t] * rs;
        ggs[t] = gg; bcs[t] = bv[t] - mu * gg;
        pls[t] = 0.f;
    }
    __syncthreads();
    const f32x4 vz = {0.f, 0.f, 0.f, 0.f};
    f32x4 acc[4][4];
    for (int m = 0; m < 4; m++)
        for (int c = 0; c < 4; c++) acc[m][c] = vz;

    // prologue: prefetch A tile for k0=0
    uint4 rA0 = {0,0,0,0}, rA1 = {0,0,0,0};
    if (arow < N_NODES) {
        const uint4* asrc = (const uint4*)(A + (size_t)arow * 256 + as_);
        rA0 = asrc[0]; rA1 = asrc[1];
    }

    for (int k0 = 0; k0 < 256; k0 += 64) {
        {
            const uint4* bsrc = (const uint4*)(Wt + brow * 256 + k0 + bo);
            uint4* bdst = (uint4*)(Bs + brow * 72 + bo);
#pragma unroll
            for (int j = 0; j < 4; j++) bdst[j] = bsrc[j];
            float f[16];
            if (arow < N_NODES) {
                unpack8(rA0, f); unpack8(rA1, f + 8);
#pragma unroll
                for (int j = 0; j < 16; j++) {
                    int c = k0 + as_ + j;
                    f[j] = fmaxf(f[j] * ggs[c] + bcs[c], 0.f);
                }
            } else {
#pragma unroll
                for (int j = 0; j < 16; j++) f[j] = 0.f;
            }
            // prefetch next k0's A
            if (k0 + 64 < 256 && arow < N_NODES) {
                const uint4* anext = (const uint4*)(A + (size_t)arow * 256 + k0 + 64 + as_);
                rA0 = anext[0]; rA1 = anext[1];
            }
            // pool: reduce over lanes with same (lane&3), add to LDS
#pragma unroll
            for (int j = 0; j < 16; j++) {
                float v = f[j];
                v += __shfl_xor(v, 4);  v += __shfl_xor(v, 8);
                v += __shfl_xor(v, 16); v += __shfl_xor(v, 32);
                if (lane < 4) atomicAdd(&pls[k0 + lane * 16 + j], v);
            }
            uint4 p0, p1;
            p0.x = packb(f[0], f[1]);   p0.y = packb(f[2], f[3]);
            p0.z = packb(f[4], f[5]);   p0.w = packb(f[6], f[7]);
            p1.x = packb(f[8], f[9]);   p1.y = packb(f[10], f[11]);
            p1.z = packb(f[12], f[13]); p1.w = packb(f[14], f[15]);
            uint4* adst = (uint4*)(As + ar * 72 + as_);
            adst[0] = p0; adst[1] = p1;
        }
        __syncthreads();
#pragma unroll
        for (int kk = 0; kk < 64; kk += 32) {
            s16x8 af[4], bf[4];
#pragma unroll
            for (int m = 0; m < 4; m++)
                af[m] = *(const s16x8*)(As + (wr * 64 + m * 16 + lm) * 72 + kk + quad * 8);
#pragma unroll
            for (int c = 0; c < 4; c++)
                bf[c] = *(const s16x8*)(Bs + (wc * 64 + c * 16 + lm) * 72 + kk + quad * 8);
#pragma unroll
            for (int c = 0; c < 4; c++)
#pragma unroll
                for (int m = 0; m < 4; m++)
                    acc[m][c] = __builtin_amdgcn_mfma_f32_16x16x32_bf16(af[m], bf[c], acc[m][c], 0, 0, 0);
        }
        __syncthreads();
    }
    if (t < 256) atomicAdd(&pool[(blockIdx.x & 7) * 256 + t], pls[t]);
#pragma unroll
    for (int m = 0; m < 4; m++) {
#pragma unroll
        for (int c = 0; c < 4; c++) {
            int col = wc * 64 + c * 16 + lm;
#pragma unroll
            for (int i = 0; i < 4; i++) {
                int row = m0 + wr * 64 + m * 16 + quad * 4 + i;
                if (row < N_NODES) Hout[(size_t)row * 256 + col] = f2b(acc[m][c][i]);
            }
        }
    }
}

// ---- GEMM layer 2 with fused BN+ReLU + pool: Hout[N,64] = relu(bn(A)) @ W2pad ----
__global__ __launch_bounds__(512) void k_gemm2_bn(const u16* __restrict__ A,
                                                  const float* __restrict__ stats,
                                                  const float* __restrict__ g,
                                                  const float* __restrict__ bv,
                                                  const u16* __restrict__ Wt,
                                                  u16* __restrict__ Hout,
                                                  float* __restrict__ pool) {
    __shared__ u16 Bs[COUTP * 72];
    __shared__ u16 As[128 * 72];
    __shared__ float ggs[256], bcs[256], pls[256];
    const int t = threadIdx.x;
    const int wave = t >> 6, lane = t & 63;
    const int lm = lane & 15, quad = lane >> 4;
    const int m0 = blockIdx.x * 128;
    const int ar = t >> 2, as_ = (t & 3) * 16;
    const int arow = m0 + ar;
    if (t < 256) {
        const float inv = 1.0f / (float)N_NODES;
        float mu = stats[t] * inv;
        float var = stats[256 + t] * inv - mu * mu;
        float rs = rsqrtf(var + EPS);
        float gg = g[t] * rs;
        ggs[t] = gg; bcs[t] = bv[t] - mu * gg;
        pls[t] = 0.f;
    }
    __syncthreads();
    const f32x4 vz = {0.f, 0.f, 0.f, 0.f};
    f32x4 acc[4]; acc[0] = vz; acc[1] = vz; acc[2] = vz; acc[3] = vz;

    uint4 rA0 = {0,0,0,0}, rA1 = {0,0,0,0};
    if (arow < N_NODES) {
        const uint4* asrc = (const uint4*)(A + (size_t)arow * 256 + as_);
        rA0 = asrc[0]; rA1 = asrc[1];
    }

    for (int k0 = 0; k0 < 256; k0 += 64) {
        {
            if (t < COUTP) {
                const uint4* bsrc = (const uint4*)(Wt + t * 256 + k0);
                uint4* bdst = (uint4*)(Bs + t * 72);
#pragma unroll
                for (int j = 0; j < 8; j++) bdst[j] = bsrc[j];
            }
            float f[16];
            if (arow < N_NODES) {
                unpack8(rA0, f); unpack8(rA1, f + 8);
#pragma unroll
                for (int j = 0; j < 16; j++) {
                    int c = k0 + as_ + j;
                    f[j] = fmaxf(f[j] * ggs[c] + bcs[c], 0.f);
                }
            } else {
#pragma unroll
                for (int j = 0; j < 16; j++) f[j] = 0.f;
            }
            if (k0 + 64 < 256 && arow < N_NODES) {
                const uint4* anext = (const uint4*)(A + (size_t)arow * 256 + k0 + 64 + as_);
                rA0 = anext[0]; rA1 = anext[1];
            }
#pragma unroll
            for (int j = 0; j < 16; j++) {
                float v = f[j];
                v += __shfl_xor(v, 4);  v += __shfl_xor(v, 8);
                v += __shfl_xor(v, 16); v += __shfl_xor(v, 32);
                if (lane < 4) atomicAdd(&pls[k0 + lane * 16 + j], v);
            }
            uint4 p0, p1;
            p0.x = packb(f[0], f[1]);   p0.y = packb(f[2], f[3]);
            p0.z = packb(f[4], f[5]);   p0.w = packb(f[6], f[7]);
            p1.x = packb(f[8], f[9]);   p1.y = packb(f[10], f[11]);
            p1.z = packb(f[12], f[13]); p1.w = packb(f[14], f[15]);
            uint4* adst = (uint4*)(As + ar * 72 + as_);
            adst[0] = p0; adst[1] = p1;
        }
        __syncthreads();
#pragma unroll
        for (int kk = 0; kk < 64; kk += 32) {
            s16x8 af = *(const s16x8*)(As + (wave * 16 + lm) * 72 + kk + quad * 8);
#pragma unroll
            for (int c = 0; c < 4; c++) {
                s16x8 bf = *(const s16x8*)(Bs + (c * 16 + lm) * 72 + kk + quad * 8);
                acc[c] = __builtin_amdgcn_mfma_f32_16x16x32_bf16(af, bf, acc[c], 0, 0, 0);
            }
        }
        __syncthreads();
    }
    if (t < 256) atomicAdd(&pool[(blockIdx.x & 7) * 256 + t], pls[t]);
#pragma unroll
    for (int c = 0; c < 4; c++) {
        int col = c * 16 + lm;
#pragma unroll
        for (int i = 0; i < 4; i++) {
            int row = m0 + wave * 16 + quad * 4 + i;
            if (row < N_NODES) Hout[(size_t)row * COUTP + col] = f2b(acc[c][i]);
        }
    }
}

// ---- aggregation L0/L1: at the random-gather memory-system wall; unchanged ----
__global__ __launch_bounds__(256) void k_agg(const u16* __restrict__ H2,
                                             const int* __restrict__ row_start,
                                             const int* __restrict__ counts,
                                             const int2* __restrict__ edata,
                                             const float* __restrict__ dis,
                                             const float* __restrict__ bias,
                                             const float* __restrict__ v2,
                                             u16* __restrict__ OutB,
                                             float* __restrict__ stats) {
    __shared__ float ls[512];
    const int t = threadIdx.x, wave = t >> 6, lane = t & 63;
    const int half = lane >> 5, hl = lane & 31;
    const int ci = hl * 8;
    const float4 bbA = *(const float4*)(bias + ci);
    const float4 bbB = *(const float4*)(bias + ci + 4);
    const float4 vvA = *(const float4*)(v2 + ci);
    const float4 vvB = *(const float4*)(v2 + ci + 4);
    float s[8], q[8];
#pragma unroll
    for (int j = 0; j < 8; j++) { s[j] = 0.f; q[j] = 0.f; }

    const int gwave = blockIdx.x * 4 + wave;      // 0..8191
    const int nid = gwave + lane * AGG_WAVES;
    const bool nv = (lane < AGG_NPW) && (nid < N_NODES);
    const int   my_rs = nv ? row_start[nid] : 0;
    const int   my_ct = nv ? counts[nid] : 0;
    const float my_dn = nv ? dis[nid] : 0.f;

    int beg = __shfl(my_rs, 0), cnt = __shfl(my_ct, 0);
    int2 my_e = {0, 0};
    if (lane < cnt) my_e = edata[beg + lane];

    for (int i = 0; i < AGG_NPW; i++) {
        const int node = gwave + i * AGG_WAVES;
        if (node >= N_NODES) break;
        const int2 cur_e = my_e;
        const int  ccnt = cnt, cbeg = beg;
        const float dn = __shfl(my_dn, i);
        const uint4 rs_ = *(const uint4*)(H2 + (size_t)node * 256 + ci);
        if (i + 1 < AGG_NPW && node + AGG_WAVES < N_NODES) {
            beg = __shfl(my_rs, i + 1);
            cnt = __shfl(my_ct, i + 1);
            int2 tmp = {0, 0};
            if (lane < cnt) tmp = edata[beg + lane];
            my_e = tmp;
        }
        const int cnt64 = ccnt < 64 ? ccnt : 64;
        const int cnt8 = (cnt64 + 7) & ~7;
        float a[8];
#pragma unroll
        for (int j = 0; j < 8; j++) a[j] = 0.f;
        float cs = 0.f;
        for (int e = 0; e < cnt8; e += 8) {
            const int   si0 = __shfl(cur_e.x, e + half);
            const int   si1 = __shfl(cur_e.x, e + 2 + half);
            const int   si2 = __shfl(cur_e.x, e + 4 + half);
            const int   si3 = __shfl(cur_e.x, e + 6 + half);
            const float cf0 = __int_as_float(__shfl(cur_e.y, e + half));
            const float cf1 = __int_as_float(__shfl(cur_e.y, e + 2 + half));
            const float cf2 = __int_as_float(__shfl(cur_e.y, e + 4 + half));
            const float cf3 = __int_as_float(__shfl(cur_e.y, e + 6 + half));
            const uint4 r0 = *(const uint4*)(H2 + (size_t)si0 * 256 + ci);
            const uint4 r1 = *(const uint4*)(H2 + (size_t)si1 * 256 + ci);
            const uint4 r2 = *(const uint4*)(H2 + (size_t)si2 * 256 + ci);
            const uint4 r3 = *(const uint4*)(H2 + (size_t)si3 * 256 + ci);
            cs += cf0 + cf1 + cf2 + cf3;
            a[0] += cf0*b2f(r0.x&0xffffu) + cf1*b2f(r1.x&0xffffu) + cf2*b2f(r2.x&0xffffu) + cf3*b2f(r3.x&0xffffu);
            a[1] += cf0*b2f(r0.x>>16)     + cf1*b2f(r1.x>>16)     + cf2*b2f(r2.x>>16)     + cf3*b2f(r3.x>>16);
            a[2] += cf0*b2f(r0.y&0xffffu) + cf1*b2f(r1.y&0xffffu) + cf2*b2f(r2.y&0xffffu) + cf3*b2f(r3.y&0xffffu);
            a[3] += cf0*b2f(r0.y>>16)     + cf1*b2f(r1.y>>16)     + cf2*b2f(r2.y>>16)     + cf3*b2f(r3.y>>16);
            a[4] += cf0*b2f(r0.z&0xffffu) + cf1*b2f(r1.z&0xffffu) + cf2*b2f(r2.z&0xffffu) + cf3*b2f(r3.z&0xffffu);
            a[5] += cf0*b2f(r0.z>>16)     + cf1*b2f(r1.z>>16)     + cf2*b2f(r2.z>>16)     + cf3*b2f(r3.z>>16);
            a[6] += cf0*b2f(r0.w&0xffffu) + cf1*b2f(r1.w&0xffffu) + cf2*b2f(r2.w&0xffffu) + cf3*b2f(r3.w&0xffffu);
            a[7] += cf0*b2f(r0.w>>16)     + cf1*b2f(r1.w>>16)     + cf2*b2f(r2.w>>16)     + cf3*b2f(r3.w>>16);
        }
        if (ccnt > 64) {
            int e2 = 64;
            for (; e2 + 2 <= ccnt; e2 += 2) {
                const int2 ed_ = edata[cbeg + e2 + half];
                const float cf = __int_as_float(ed_.y);
                const uint4 r = *(const uint4*)(H2 + (size_t)ed_.x * 256 + ci);
                cs += cf;
                a[0] += cf*b2f(r.x&0xffffu); a[1] += cf*b2f(r.x>>16);
                a[2] += cf*b2f(r.y&0xffffu); a[3] += cf*b2f(r.y>>16);
                a[4] += cf*b2f(r.z&0xffffu); a[5] += cf*b2f(r.z>>16);
                a[6] += cf*b2f(r.w&0xffffu); a[7] += cf*b2f(r.w>>16);
            }
            if (e2 < ccnt && half == 0) {
                const int2 ed_ = edata[cbeg + e2];
                const float cf = __int_as_float(ed_.y);
                const uint4 r = *(const uint4*)(H2 + (size_t)ed_.x * 256 + ci);
                cs += cf;
                a[0] += cf*b2f(r.x&0xffffu); a[1] += cf*b2f(r.x>>16);
                a[2] += cf*b2f(r.y&0xffffu); a[3] += cf*b2f(r.y>>16);
                a[4] += cf*b2f(r.z&0xffffu); a[5] += cf*b2f(r.z>>16);
                a[6] += cf*b2f(r.w&0xffffu); a[7] += cf*b2f(r.w>>16);
            }
        }
        cs += __shfl_xor(cs, 32);
#pragma unroll
        for (int j = 0; j < 8; j++) a[j] += __shfl_xor(a[j], 32);
        const float sc = dn * dn, cv = cs + sc;
        const float f0 = a[0] + sc*b2f(rs_.x&0xffffu) + cv*vvA.x + bbA.x;
        const float f1 = a[1] + sc*b2f(rs_.x>>16)     + cv*vvA.y + bbA.y;
        const float f2 = a[2] + sc*b2f(rs_.y&0xffffu) + cv*vvA.z + bbA.z;
        const float f3 = a[3] + sc*b2f(rs_.y>>16)     + cv*vvA.w + bbA.w;
        const float f4 = a[4] + sc*b2f(rs_.z&0xffffu) + cv*vvB.x + bbB.x;
        const float f5 = a[5] + sc*b2f(rs_.z>>16)     + cv*vvB.y + bbB.y;
        const float f6 = a[6] + sc*b2f(rs_.w&0xffffu) + cv*vvB.z + bbB.z;
        const float f7 = a[7] + sc*b2f(rs_.w>>16)     + cv*vvB.w + bbB.w;
        if (half == 0) {
            uint4 o;
            o.x = packb(f0, f1); o.y = packb(f2, f3);
            o.z = packb(f4, f5); o.w = packb(f6, f7);
            *(uint4*)(OutB + (size_t)node * 256 + ci) = o;
        }
        s[0] += f0; q[0] += f0*f0;  s[1] += f1; q[1] += f1*f1;
        s[2] += f2; q[2] += f2*f2;  s[3] += f3; q[3] += f3*f3;
        s[4] += f4; q[4] += f4*f4;  s[5] += f5; q[5] += f5*f5;
        s[6] += f6; q[6] += f6*f6;  s[7] += f7; q[7] += f7*f7;
    }
    ls[t] = 0.f; ls[256 + t] = 0.f;
    __syncthreads();
    if (half == 0) {
#pragma unroll
        for (int j = 0; j < 8; j++) {
            atomicAdd(&ls[ci + j], s[j]);
            atomicAdd(&ls[256 + ci + j], q[j]);
        }
    }
    __syncthreads();
    atomicAdd(&stats[t], ls[t]);
    atomicAdd(&stats[256 + t], ls[256 + t]);
}

// ---------------- virtual node update + v2_next = vx_new @ Wnext ----------------
__global__ void k_vx(const float* __restrict__ pool, const float* __restrict__ vx_old,
                     const float* __restrict__ vnW, const float* __restrict__ vnb,
                     const float* __restrict__ lng, const float* __restrict__ lnb,
                     float* __restrict__ vx_new,
                     const float* __restrict__ Wnext, int ncn, int npn,
                     float* __restrict__ v2n) {
    __shared__ float s[256];
    __shared__ float red[256];
    int t = threadIdx.x;
    float pv = 0.f;
#pragma unroll
    for (int r = 0; r < 8; r++) pv += pool[r * 256 + t];
    s[t] = pv + vx_old[t];
    __syncthreads();
    float y = vnb[t];
    for (int k = 0; k < 256; k++) y += s[k] * vnW[k * 256 + t];
    red[t] = y; __syncthreads();
    for (int off = 128; off > 0; off >>= 1) {
        if (t < off) red[t] += red[t + off];
        __syncthreads();
    }
    float mu = red[0] * (1.f / 256.f);
    __syncthreads();
    float d = y - mu;
    red[t] = d * d; __syncthreads();
    for (int off = 128; off > 0; off >>= 1) {
        if (t < off) red[t] += red[t + off];
        __syncthreads();
    }
    float var = red[0] * (1.f / 256.f);
    float v = fmaxf(d * rsqrtf(var + EPS) * lng[t] + lnb[t], 0.f);
    vx_new[t] = v;
    __syncthreads();
    s[t] = v;
    __syncthreads();
    float acc = 0.f;
    if (t < ncn) {
        for (int k = 0; k < 256; k++) acc += s[k] * Wnext[k * ncn + t];
    }
    if (t < npn) v2n[t] = acc;
}

// ---- layer-2 aggregation + (cs+dn^2)*v2 fold + log_softmax ----
// COUTP=64: each gathered row is exactly one 128-B cache line.
__global__ __launch_bounds__(256) void k_agg2(const u16* __restrict__ H2,
                                              const int* __restrict__ row_start,
                                              const int* __restrict__ counts,
                                              const int2* __restrict__ edata,
                                              const float* __restrict__ dis,
                                              const float* __restrict__ bias,
                                              const float* __restrict__ v2,
                                              float* __restrict__ OutF) {
    const int t = threadIdx.x, wave = t >> 6, lane = t & 63;
    const int half = lane >> 5, hl = lane & 31;
    const bool cact = hl < 20;
    const int c0 = 2 * hl;
    float bb0 = 0.f, bb1 = 0.f, vv0 = 0.f, vv1 = 0.f;
    if (cact) {
        float2 bv = *(const float2*)(bias + c0); bb0 = bv.x; bb1 = bv.y;
        float2 vvv = *(const float2*)(v2 + c0);  vv0 = vvv.x; vv1 = vvv.y;
    }
    const int nbase = blockIdx.x * 16 + wave * 4;
    for (int i = 0; i < 4; i++) {
        const int node = nbase + i;
        const int beg = row_start[node], cnt = counts[node];
        const float dn = dis[node];
        float a0 = 0.f, a1 = 0.f, cs = 0.f;
        int e = half;
        for (; e + 6 < cnt; e += 8) {
            int2 ea = edata[beg+e],   eb = edata[beg+e+2];
            int2 ec = edata[beg+e+4], ed = edata[beg+e+6];
            float ca = __int_as_float(ea.y), cb = __int_as_float(eb.y);
            float cc = __int_as_float(ec.y), cd = __int_as_float(ed.y);
            u32 ra = 0, rb = 0, rc = 0, rd = 0;
            if (cact) {
                ra = *(const u32*)(H2 + (size_t)ea.x * COUTP + c0);
                rb = *(const u32*)(H2 + (size_t)eb.x * COUTP + c0);
                rc = *(const u32*)(H2 + (size_t)ec.x * COUTP + c0);
                rd = *(const u32*)(H2 + (size_t)ed.x * COUTP + c0);
            }
            cs += ca + cb + cc + cd;
            a0 += ca*b2f(ra&0xffffu) + cb*b2f(rb&0xffffu) + cc*b2f(rc&0xffffu) + cd*b2f(rd&0xffffu);
            a1 += ca*b2f(ra>>16)     + cb*b2f(rb>>16)     + cc*b2f(rc>>16)     + cd*b2f(rd>>16);
        }
        for (; e < cnt; e += 2) {
            int2 ea = edata[beg+e];
            float ca = __int_as_float(ea.y);
            u32 ra = cact ? *(const u32*)(H2 + (size_t)ea.x * COUTP + c0) : 0u;
            cs += ca;
            a0 += ca*b2f(ra&0xffffu); a1 += ca*b2f(ra>>16);
        }
        a0 += __shfl_xor(a0, 32);
        a1 += __shfl_xor(a1, 32);
        cs += __shfl_xor(cs, 32);
        const float sc = dn * dn;
        u32 rs_ = cact ? *(const u32*)(H2 + (size_t)node * COUTP + c0) : 0u;
        float h0 = a0 + sc*b2f(rs_&0xffffu) + (cs+sc)*vv0 + bb0;
        float h1 = a1 + sc*b2f(rs_>>16)     + (cs+sc)*vv1 + bb1;
        float m = cact ? fmaxf(h0, h1) : -3.0e38f;
#pragma unroll
        for (int off = 16; off > 0; off >>= 1) m = fmaxf(m, __shfl_xor(m, off));
        float ex = cact ? (expf(h0 - m) + expf(h1 - m)) : 0.f;
        float se = ex;
#pragma unroll
        for (int off = 16; off > 0; off >>= 1) se += __shfl_xor(se, off);
        float lg = logf(se);
        if (cact && half == 0) {
            float2 o = {h0 - m - lg, h1 - m - lg};
            *(float2*)(OutF + (size_t)node * COUT + c0) = o;
        }
    }
}

extern "C" void kernel_launch(void* const* d_in, const int* in_sizes, int n_in,
                              void* d_out, int out_size, void* d_ws, size_t ws_size,
                              hipStream_t stream) {
    const float* x   = (const float*)d_in[0];
    const int*   ei  = (const int*)d_in[1];
    const int*   esrc = ei;
    const int*   edst = ei + N_EDGES;
    const float* W0 = (const float*)d_in[2];  const float* b0 = (const float*)d_in[3];
    const float* W1 = (const float*)d_in[4];  const float* b1 = (const float*)d_in[5];
    const float* W2 = (const float*)d_in[6];  const float* b2 = (const float*)d_in[7];
    const float* bg0 = (const float*)d_in[8]; const float* bb0 = (const float*)d_in[9];
    const float* bg1 = (const float*)d_in[10]; const float* bb1 = (const float*)d_in[11];
    const float* vn_emb = (const float*)d_in[12];
    const float* vW0 = (const float*)d_in[13]; const float* vb0 = (const float*)d_in[14];
    const float* lg0 = (const float*)d_in[15]; const float* lb0 = (const float*)d_in[16];
    const float* vW1 = (const float*)d_in[17]; const float* vb1 = (const float*)d_in[18];
    const float* lg1 = (const float*)d_in[19]; const float* lb1 = (const float*)d_in[20];

    char* w = (char*)d_ws;
    auto alloc = [&](size_t bytes) { void* p = (void*)w; w += ((bytes + 255) / 256) * 256; return p; };
    u16* H2    = (u16*)alloc((size_t)N_NODES * 256 * 2);
    u16* OutB  = (u16*)alloc((size_t)N_NODES * 256 * 2);
    int2* edata = (int2*)alloc((size_t)N_EDGES * 8);
    int* counts = (int*)alloc((size_t)N_NODES * 4);
    int* rowst  = (int*)alloc((size_t)N_NODES * 4);
    int* cursor = (int*)alloc((size_t)N_NODES * 4);
    float* dis  = (float*)alloc((size_t)N_NODES * 4);
    u16* Wtb0 = (u16*)alloc(256 * 256 * 2);
    u16* Wtb1 = (u16*)alloc(256 * 256 * 2);
    u16* Wt2b = (u16*)alloc(COUTP * 256 * 2);
    int* scanblk = (int*)alloc(128 * 4);
    float* statsA = (float*)alloc(2560 * 4);   // sum[256], sq[256], pool[8*256]
    float* statsB = (float*)alloc(2560 * 4);
    float* vxA = (float*)alloc(256 * 4);
    float* vxB = (float*)alloc(256 * 4);
    float* v20 = (float*)alloc(256 * 4);
    float* v21 = (float*)alloc(256 * 4);
    float* v22 = (float*)alloc(COUTP * 4);
    (void)ws_size; (void)in_sizes; (void)n_in; (void)out_size;

    // ---- fused prep: transposes + vecmat + zeroing ----
    k_prep<<<PREP_BLOCKS, 256, 0, stream>>>(W0, W1, W2, Wtb0, Wtb1, Wt2b,
                                            vn_emb, v20, counts, statsA, statsB);
    // ---- graph prep: degrees + CSR + packed edge data ----
    k_count<<<(N_EDGES + 255) / 256, 256, 0, stream>>>(edst, counts);
    k_scan1<<<NSCAN_BLK, 256, 0, stream>>>(counts, rowst, scanblk);
    k_scan3<<<(N_NODES + 255) / 256, 256, 0, stream>>>(rowst, scanblk, cursor, counts, dis);
    k_fill<<<(N_EDGES + 255) / 256, 256, 0, stream>>>(esrc, edst, cursor, edata, dis);

    const int gemmblk = (N_NODES + 127) / 128;

    // ---- layer 0 ----
    k_gemm_f32a<<<gemmblk, 512, 0, stream>>>(x, Wtb0, H2);
    k_agg<<<AGG_BLOCKS, 256, 0, stream>>>(H2, rowst, counts, edata, dis, b0, v20, OutB, statsA);
    // ---- layer 1 (BN0+ReLU+pool fused into gemm A-staging) ----
    k_gemm_bn<<<gemmblk, 512, 0, stream>>>(OutB, statsA, bg0, bb0, Wtb1, H2, statsA + 512);
    k_vx<<<1, 256, 0, stream>>>(statsA + 512, vn_emb, vW0, vb0, lg0, lb0, vxA, W1, 256, 256, v21);
    k_agg<<<AGG_BLOCKS, 256, 0, stream>>>(H2, rowst, counts, edata, dis, b1, v21, OutB, statsB);
    // ---- layer 2 ----
    k_gemm2_bn<<<gemmblk, 512, 0, stream>>>(OutB, statsB, bg1, bb1, Wt2b, H2, statsB + 512);
    k_vx<<<1, 256, 0, stream>>>(statsB + 512, vxA, vW1, vb1, lg1, lb1, vxB, W2, COUT, COUTP, v22);
    k_agg2<<<N_NODES / 16, 256, 0, stream>>>(H2, rowst, counts, edata, dis, b2, v22, (float*)d_out);
}

// Round 8
// 692.630 us; speedup vs baseline: 1.0731x; 1.0660x over previous
//
#include <hip/hip_runtime.h>
#include <hip/hip_bf16.h>
#include <cstdint>

#define N_NODES 100000
#define N_EDGES 800000
#define CH      256
#define COUT    40
#define COUTP   48
#define EPS     1e-5f
#define SCAN_CHUNK 1024
#define NSCAN_BLK  98   // ceil(100000/1024)
#define AGG_NPW 16      // nodes per wave in k_agg (strided)
#define AGG_BLOCKS 2048 // full residency: 8 blocks/CU * 256 CU
#define AGG_WAVES  (AGG_BLOCKS * 4)   // 8192 waves; stride for node assignment
#define GEMMBLK ((N_NODES + 127) / 128)          // 782
#define FILLBLK ((N_EDGES + 511) / 512)          // 1563

typedef unsigned short u16;
typedef unsigned int   u32;
typedef short s16x8 __attribute__((ext_vector_type(8)));
typedef float f32x4 __attribute__((ext_vector_type(4)));

__device__ __forceinline__ float b2f(u32 u) { return __uint_as_float(u << 16); }
__device__ __forceinline__ u16 f2b(float f) {
    u32 u = __float_as_uint(f);
    u32 r = (u + 0x7fffu + ((u >> 16) & 1u)) >> 16;   // RNE
    return (u16)r;
}
__device__ __forceinline__ u32 packb(float a, float b) {
    return (u32)f2b(a) | ((u32)f2b(b) << 16);
}
__device__ __forceinline__ void unpack8(uint4 v, float* f) {
    f[0] = b2f(v.x & 0xffffu); f[1] = b2f(v.x >> 16);
    f[2] = b2f(v.y & 0xffffu); f[3] = b2f(v.y >> 16);
    f[4] = b2f(v.z & 0xffffu); f[5] = b2f(v.z >> 16);
    f[6] = b2f(v.w & 0xffffu); f[7] = b2f(v.w >> 16);
}

// ---------------- CSR build ----------------
__global__ void k_count(const int* __restrict__ dst, int* __restrict__ counts) {
    int e = blockIdx.x * 256 + threadIdx.x;
    if (e < N_EDGES) atomicAdd(&counts[dst[e]], 1);
}

__global__ void k_scan1(const int* __restrict__ counts, int* __restrict__ partial,
                        int* __restrict__ blocksums) {
    __shared__ int sdata[256];
    int base = blockIdx.x * SCAN_CHUNK;
    int t = threadIdx.x;
    int v[4]; int s = 0;
    for (int j = 0; j < 4; j++) {
        int i = base + t * 4 + j;
        v[j] = (i < N_NODES) ? counts[i] : 0;
        s += v[j];
    }
    sdata[t] = s; __syncthreads();
    for (int off = 1; off < 256; off <<= 1) {
        int x = (t >= off) ? sdata[t - off] : 0;
        __syncthreads();
        sdata[t] += x;
        __syncthreads();
    }
    int incl = sdata[t];
    int run = incl - s;
    if (t == 255) blocksums[blockIdx.x] = incl;
    for (int j = 0; j < 4; j++) {
        int i = base + t * 4 + j;
        if (i < N_NODES) partial[i] = run;
        run += v[j];
    }
}

// scan3 with the 98-element block-sum scan folded in (replaces k_scan2)
__global__ void k_scan3(int* __restrict__ row_start, const int* __restrict__ blocksums,
                        int* __restrict__ cursor, const int* __restrict__ counts,
                        float* __restrict__ dis) {
    __shared__ int sd[128], raw[128];
    int t = threadIdx.x;
    if (t < 128) {
        int v = (t < NSCAN_BLK) ? blocksums[t] : 0;
        sd[t] = v; raw[t] = v;
    }
    __syncthreads();
    for (int off = 1; off < 128; off <<= 1) {
        int x = (t < 128 && t >= off) ? sd[t - off] : 0;
        __syncthreads();
        if (t < 128) sd[t] += x;
        __syncthreads();
    }
    int i = blockIdx.x * 256 + t;
    if (i < N_NODES) {
        int j = i >> 10;
        int v = row_start[i] + (sd[j] - raw[j]);
        row_start[i] = v;
        cursor[i] = v;
        dis[i] = rsqrtf(1.0f + (float)counts[i]);
    }
}

// ---------------- fused prep: weight transposes + vecmat + zeroing ----------------
#define PREP_ZBASE (513 + COUTP)
#define PREP_ZN    (N_NODES + 2560 + 2560)
#define PREP_BLOCKS (PREP_ZBASE + (PREP_ZN + 255) / 256)
__global__ void k_prep(const float* __restrict__ W0, const float* __restrict__ W1,
                       const float* __restrict__ W2,
                       u16* __restrict__ T0, u16* __restrict__ T1, u16* __restrict__ T2,
                       const float* __restrict__ vec, float* __restrict__ v20,
                       int* __restrict__ counts, float* __restrict__ statsA,
                       float* __restrict__ statsB) {
    __shared__ float s[256];
    int b = blockIdx.x, t = threadIdx.x;
    if (b < 256) {
        T0[b * 256 + t] = f2b(W0[t * 256 + b]);
    } else if (b < 512) {
        int n = b - 256;
        T1[n * 256 + t] = f2b(W1[t * 256 + n]);
    } else if (b < 512 + COUTP) {
        int n = b - 512;
        T2[n * 256 + t] = f2b(n < COUT ? W2[t * COUT + n] : 0.f);
    } else if (b == 512 + COUTP) {
        s[t] = vec[t];
        __syncthreads();
        float acc = 0.f;
        for (int k = 0; k < 256; k++) acc += s[k] * W0[k * 256 + t];
        v20[t] = acc;
    } else {
        int idx = (b - PREP_ZBASE) * 256 + t;
        if (idx < N_NODES) counts[idx] = 0;
        else if ((idx -= N_NODES) < 2560) statsA[idx] = 0.f;
        else if ((idx -= 2560) < 2560) statsB[idx] = 0.f;
    }
}

// ---------------- fused GEMM layer-0 + edge fill ----------------
// Blocks [0, GEMMBLK): 128x256 GEMM tile, Hout[N,256] = bf16(x) @ W (r5 body).
// Blocks [GEMMBLK, GEMMBLK+FILLBLK): k_fill — independent of the GEMM, rides
// under it instead of serializing after scan3 (one fewer dispatch + overlap).
__global__ __launch_bounds__(512) void k_gemm0_fill(const float* __restrict__ A,
                                                    const u16* __restrict__ Wt,
                                                    u16* __restrict__ Hout,
                                                    const int* __restrict__ src,
                                                    const int* __restrict__ dst,
                                                    int* __restrict__ cursor,
                                                    int2* __restrict__ edata,
                                                    const float* __restrict__ dis) {
    __shared__ u16 Bs[256 * 72];
    __shared__ u16 As[128 * 72];
    if (blockIdx.x >= GEMMBLK) {
        int e = (blockIdx.x - GEMMBLK) * 512 + threadIdx.x;
        if (e < N_EDGES) {
            int d = dst[e], s = src[e];
            int p = atomicAdd(&cursor[d], 1);
            int2 v; v.x = s; v.y = __float_as_int(dis[s] * dis[d]);
            edata[p] = v;
        }
        return;
    }
    const int t = threadIdx.x;
    const int wave = t >> 6, lane = t & 63;
    const int lm = lane & 15, quad = lane >> 4;
    const int wr = wave & 1, wc = wave >> 1;
    const int m0 = blockIdx.x * 128;
    const int ar = t >> 2, as_ = (t & 3) * 16;
    const int arow = m0 + ar;
    const int brow = t >> 1, bo = (t & 1) * 32;
    const f32x4 vz = {0.f, 0.f, 0.f, 0.f};
    f32x4 acc[4][4];
    for (int m = 0; m < 4; m++)
        for (int c = 0; c < 4; c++) acc[m][c] = vz;

    for (int k0 = 0; k0 < 256; k0 += 64) {
        {
            const uint4* bsrc = (const uint4*)(Wt + brow * 256 + k0 + bo);
            uint4* bdst = (uint4*)(Bs + brow * 72 + bo);
#pragma unroll
            for (int j = 0; j < 4; j++) bdst[j] = bsrc[j];
            uint4 p0 = {0,0,0,0}, p1 = {0,0,0,0};
            if (arow < N_NODES) {
                const float4* asrc = (const float4*)(A + (size_t)arow * 256 + k0 + as_);
                float4 x0 = asrc[0], x1 = asrc[1], x2 = asrc[2], x3 = asrc[3];
                p0.x = packb(x0.x, x0.y); p0.y = packb(x0.z, x0.w);
                p0.z = packb(x1.x, x1.y); p0.w = packb(x1.z, x1.w);
                p1.x = packb(x2.x, x2.y); p1.y = packb(x2.z, x2.w);
                p1.z = packb(x3.x, x3.y); p1.w = packb(x3.z, x3.w);
            }
            uint4* adst = (uint4*)(As + ar * 72 + as_);
            adst[0] = p0; adst[1] = p1;
        }
        __syncthreads();
#pragma unroll
        for (int kk = 0; kk < 64; kk += 32) {
            s16x8 af[4], bf[4];
#pragma unroll
            for (int m = 0; m < 4; m++)
                af[m] = *(const s16x8*)(As + (wr * 64 + m * 16 + lm) * 72 + kk + quad * 8);
#pragma unroll
            for (int c = 0; c < 4; c++)
                bf[c] = *(const s16x8*)(Bs + (wc * 64 + c * 16 + lm) * 72 + kk + quad * 8);
#pragma unroll
            for (int c = 0; c < 4; c++)
#pragma unroll
                for (int m = 0; m < 4; m++)
                    acc[m][c] = __builtin_amdgcn_mfma_f32_16x16x32_bf16(af[m], bf[c], acc[m][c], 0, 0, 0);
        }
        __syncthreads();
    }
#pragma unroll
    for (int m = 0; m < 4; m++) {
#pragma unroll
        for (int c = 0; c < 4; c++) {
            int col = wc * 64 + c * 16 + lm;
#pragma unroll
            for (int i = 0; i < 4; i++) {
                int row = m0 + wr * 64 + m * 16 + quad * 4 + i;
                if (row < N_NODES) Hout[(size_t)row * 256 + col] = f2b(acc[m][c][i]);
            }
        }
    }
}

// ---- GEMM with fused BN+ReLU on A + pool: Hout = relu(bn(A)) @ W; pool += colsum ----
__global__ __launch_bounds__(512) void k_gemm_bn(const u16* __restrict__ A,
                                                 const float* __restrict__ stats,
                                                 const float* __restrict__ g,
                                                 const float* __restrict__ bv,
                                                 const u16* __restrict__ Wt,
                                                 u16* __restrict__ Hout,
                                                 float* __restrict__ pool) {
    __shared__ u16 Bs[256 * 72];
    __shared__ u16 As[128 * 72];
    __shared__ float ggs[256], bcs[256], pls[256];
    const int t = threadIdx.x;
    const int wave = t >> 6, lane = t & 63;
    const int lm = lane & 15, quad = lane >> 4;
    const int wr = wave & 1, wc = wave >> 1;
    const int m0 = blockIdx.x * 128;
    const int ar = t >> 2, as_ = (t & 3) * 16;
    const int arow = m0 + ar;
    const int brow = t >> 1, bo = (t & 1) * 32;
    if (t < 256) {
        const float inv = 1.0f / (float)N_NODES;
        float mu = stats[t] * inv;
        float var = stats[256 + t] * inv - mu * mu;
        float rs = rsqrtf(var + EPS);
        float gg = g[t] * rs;
        ggs[t] = gg; bcs[t] = bv[t] - mu * gg;
        pls[t] = 0.f;
    }
    __syncthreads();
    const f32x4 vz = {0.f, 0.f, 0.f, 0.f};
    f32x4 acc[4][4];
    for (int m = 0; m < 4; m++)
        for (int c = 0; c < 4; c++) acc[m][c] = vz;

    for (int k0 = 0; k0 < 256; k0 += 64) {
        {
            const uint4* bsrc = (const uint4*)(Wt + brow * 256 + k0 + bo);
            uint4* bdst = (uint4*)(Bs + brow * 72 + bo);
#pragma unroll
            for (int j = 0; j < 4; j++) bdst[j] = bsrc[j];
            float f[16];
            if (arow < N_NODES) {
                const uint4* asrc = (const uint4*)(A + (size_t)arow * 256 + k0 + as_);
                uint4 r0 = asrc[0], r1 = asrc[1];
                unpack8(r0, f); unpack8(r1, f + 8);
#pragma unroll
                for (int j = 0; j < 16; j++) {
                    int c = k0 + as_ + j;
                    f[j] = fmaxf(f[j] * ggs[c] + bcs[c], 0.f);
                }
            } else {
#pragma unroll
                for (int j = 0; j < 16; j++) f[j] = 0.f;
            }
            // pool: reduce over lanes with same (lane&3), add to LDS
#pragma unroll
            for (int j = 0; j < 16; j++) {
                float v = f[j];
                v += __shfl_xor(v, 4);  v += __shfl_xor(v, 8);
                v += __shfl_xor(v, 16); v += __shfl_xor(v, 32);
                if (lane < 4) atomicAdd(&pls[k0 + lane * 16 + j], v);
            }
            uint4 p0, p1;
            p0.x = packb(f[0], f[1]);   p0.y = packb(f[2], f[3]);
            p0.z = packb(f[4], f[5]);   p0.w = packb(f[6], f[7]);
            p1.x = packb(f[8], f[9]);   p1.y = packb(f[10], f[11]);
            p1.z = packb(f[12], f[13]); p1.w = packb(f[14], f[15]);
            uint4* adst = (uint4*)(As + ar * 72 + as_);
            adst[0] = p0; adst[1] = p1;
        }
        __syncthreads();
#pragma unroll
        for (int kk = 0; kk < 64; kk += 32) {
            s16x8 af[4], bf[4];
#pragma unroll
            for (int m = 0; m < 4; m++)
                af[m] = *(const s16x8*)(As + (wr * 64 + m * 16 + lm) * 72 + kk + quad * 8);
#pragma unroll
            for (int c = 0; c < 4; c++)
                bf[c] = *(const s16x8*)(Bs + (wc * 64 + c * 16 + lm) * 72 + kk + quad * 8);
#pragma unroll
            for (int c = 0; c < 4; c++)
#pragma unroll
                for (int m = 0; m < 4; m++)
                    acc[m][c] = __builtin_amdgcn_mfma_f32_16x16x32_bf16(af[m], bf[c], acc[m][c], 0, 0, 0);
        }
        __syncthreads();
    }
    if (t < 256) atomicAdd(&pool[(blockIdx.x & 7) * 256 + t], pls[t]);
#pragma unroll
    for (int m = 0; m < 4; m++) {
#pragma unroll
        for (int c = 0; c < 4; c++) {
            int col = wc * 64 + c * 16 + lm;
#pragma unroll
            for (int i = 0; i < 4; i++) {
                int row = m0 + wr * 64 + m * 16 + quad * 4 + i;
                if (row < N_NODES) Hout[(size_t)row * 256 + col] = f2b(acc[m][c][i]);
            }
        }
    }
}

// ---- GEMM layer 2 with fused BN+ReLU + pool: Hout[N,48] = relu(bn(A)) @ W2pad ----
__global__ __launch_bounds__(512) void k_gemm2_bn(const u16* __restrict__ A,
                                                  const float* __restrict__ stats,
                                                  const float* __restrict__ g,
                                                  const float* __restrict__ bv,
                                                  const u16* __restrict__ Wt,
                                                  u16* __restrict__ Hout,
                                                  float* __restrict__ pool) {
    __shared__ u16 Bs[48 * 72];
    __shared__ u16 As[128 * 72];
    __shared__ float ggs[256], bcs[256], pls[256];
    const int t = threadIdx.x;
    const int wave = t >> 6, lane = t & 63;
    const int lm = lane & 15, quad = lane >> 4;
    const int m0 = blockIdx.x * 128;
    const int ar = t >> 2, as_ = (t & 3) * 16;
    const int arow = m0 + ar;
    if (t < 256) {
        const float inv = 1.0f / (float)N_NODES;
        float mu = stats[t] * inv;
        float var = stats[256 + t] * inv - mu * mu;
        float rs = rsqrtf(var + EPS);
        float gg = g[t] * rs;
        ggs[t] = gg; bcs[t] = bv[t] - mu * gg;
        pls[t] = 0.f;
    }
    __syncthreads();
    const f32x4 vz = {0.f, 0.f, 0.f, 0.f};
    f32x4 acc[3]; acc[0] = vz; acc[1] = vz; acc[2] = vz;

    for (int k0 = 0; k0 < 256; k0 += 64) {
        {
            if (t < 48) {
                const uint4* bsrc = (const uint4*)(Wt + t * 256 + k0);
                uint4* bdst = (uint4*)(Bs + t * 72);
#pragma unroll
                for (int j = 0; j < 8; j++) bdst[j] = bsrc[j];
            }
            float f[16];
            if (arow < N_NODES) {
                const uint4* asrc = (const uint4*)(A + (size_t)arow * 256 + k0 + as_);
                uint4 r0 = asrc[0], r1 = asrc[1];
                unpack8(r0, f); unpack8(r1, f + 8);
#pragma unroll
                for (int j = 0; j < 16; j++) {
                    int c = k0 + as_ + j;
                    f[j] = fmaxf(f[j] * ggs[c] + bcs[c], 0.f);
                }
            } else {
#pragma unroll
                for (int j = 0; j < 16; j++) f[j] = 0.f;
            }
#pragma unroll
            for (int j = 0; j < 16; j++) {
                float v = f[j];
                v += __shfl_xor(v, 4);  v += __shfl_xor(v, 8);
                v += __shfl_xor(v, 16); v += __shfl_xor(v, 32);
                if (lane < 4) atomicAdd(&pls[k0 + lane * 16 + j], v);
            }
            uint4 p0, p1;
            p0.x = packb(f[0], f[1]);   p0.y = packb(f[2], f[3]);
            p0.z = packb(f[4], f[5]);   p0.w = packb(f[6], f[7]);
            p1.x = packb(f[8], f[9]);   p1.y = packb(f[10], f[11]);
            p1.z = packb(f[12], f[13]); p1.w = packb(f[14], f[15]);
            uint4* adst = (uint4*)(As + ar * 72 + as_);
            adst[0] = p0; adst[1] = p1;
        }
        __syncthreads();
#pragma unroll
        for (int kk = 0; kk < 64; kk += 32) {
            s16x8 af = *(const s16x8*)(As + (wave * 16 + lm) * 72 + kk + quad * 8);
#pragma unroll
            for (int c = 0; c < 3; c++) {
                s16x8 bf = *(const s16x8*)(Bs + (c * 16 + lm) * 72 + kk + quad * 8);
                acc[c] = __builtin_amdgcn_mfma_f32_16x16x32_bf16(af, bf, acc[c], 0, 0, 0);
            }
        }
        __syncthreads();
    }
    if (t < 256) atomicAdd(&pool[(blockIdx.x & 7) * 256 + t], pls[t]);
#pragma unroll
    for (int c = 0; c < 3; c++) {
        int col = c * 16 + lm;
#pragma unroll
        for (int i = 0; i < 4; i++) {
            int row = m0 + wave * 16 + quad * 4 + i;
            if (row < N_NODES) Hout[(size_t)row * COUTP + col] = f2b(acc[c][i]);
        }
    }
}

// ---- aggregation L0/L1: at the random-gather memory-system wall; unchanged ----
__global__ __launch_bounds__(256) void k_agg(const u16* __restrict__ H2,
                                             const int* __restrict__ row_start,
                                             const int* __restrict__ counts,
                                             const int2* __restrict__ edata,
                                             const float* __restrict__ dis,
                                             const float* __restrict__ bias,
                                             const float* __restrict__ v2,
                                             u16* __restrict__ OutB,
                                             float* __restrict__ stats) {
    __shared__ float ls[512];
    const int t = threadIdx.x, wave = t >> 6, lane = t & 63;
    const int half = lane >> 5, hl = lane & 31;
    const int ci = hl * 8;
    const float4 bbA = *(const float4*)(bias + ci);
    const float4 bbB = *(const float4*)(bias + ci + 4);
    const float4 vvA = *(const float4*)(v2 + ci);
    const float4 vvB = *(const float4*)(v2 + ci + 4);
    float s[8], q[8];
#pragma unroll
    for (int j = 0; j < 8; j++) { s[j] = 0.f; q[j] = 0.f; }

    const int gwave = blockIdx.x * 4 + wave;      // 0..8191
    const int nid = gwave + lane * AGG_WAVES;
    const bool nv = (lane < AGG_NPW) && (nid < N_NODES);
    const int   my_rs = nv ? row_start[nid] : 0;
    const int   my_ct = nv ? counts[nid] : 0;
    const float my_dn = nv ? dis[nid] : 0.f;

    int beg = __shfl(my_rs, 0), cnt = __shfl(my_ct, 0);
    int2 my_e = {0, 0};
    if (lane < cnt) my_e = edata[beg + lane];

    for (int i = 0; i < AGG_NPW; i++) {
        const int node = gwave + i * AGG_WAVES;
        if (node >= N_NODES) break;
        const int2 cur_e = my_e;
        const int  ccnt = cnt, cbeg = beg;
        const float dn = __shfl(my_dn, i);
        const uint4 rs_ = *(const uint4*)(H2 + (size_t)node * 256 + ci);
        if (i + 1 < AGG_NPW && node + AGG_WAVES < N_NODES) {
            beg = __shfl(my_rs, i + 1);
            cnt = __shfl(my_ct, i + 1);
            int2 tmp = {0, 0};
            if (lane < cnt) tmp = edata[beg + lane];
            my_e = tmp;
        }
        const int cnt64 = ccnt < 64 ? ccnt : 64;
        const int cnt8 = (cnt64 + 7) & ~7;
        float a[8];
#pragma unroll
        for (int j = 0; j < 8; j++) a[j] = 0.f;
        float cs = 0.f;
        for (int e = 0; e < cnt8; e += 8) {
            const int   si0 = __shfl(cur_e.x, e + half);
            const int   si1 = __shfl(cur_e.x, e + 2 + half);
            const int   si2 = __shfl(cur_e.x, e + 4 + half);
            const int   si3 = __shfl(cur_e.x, e + 6 + half);
            const float cf0 = __int_as_float(__shfl(cur_e.y, e + half));
            const float cf1 = __int_as_float(__shfl(cur_e.y, e + 2 + half));
            const float cf2 = __int_as_float(__shfl(cur_e.y, e + 4 + half));
            const float cf3 = __int_as_float(__shfl(cur_e.y, e + 6 + half));
            const uint4 r0 = *(const uint4*)(H2 + (size_t)si0 * 256 + ci);
            const uint4 r1 = *(const uint4*)(H2 + (size_t)si1 * 256 + ci);
            const uint4 r2 = *(const uint4*)(H2 + (size_t)si2 * 256 + ci);
            const uint4 r3 = *(const uint4*)(H2 + (size_t)si3 * 256 + ci);
            cs += cf0 + cf1 + cf2 + cf3;
            a[0] += cf0*b2f(r0.x&0xffffu) + cf1*b2f(r1.x&0xffffu) + cf2*b2f(r2.x&0xffffu) + cf3*b2f(r3.x&0xffffu);
            a[1] += cf0*b2f(r0.x>>16)     + cf1*b2f(r1.x>>16)     + cf2*b2f(r2.x>>16)     + cf3*b2f(r3.x>>16);
            a[2] += cf0*b2f(r0.y&0xffffu) + cf1*b2f(r1.y&0xffffu) + cf2*b2f(r2.y&0xffffu) + cf3*b2f(r3.y&0xffffu);
            a[3] += cf0*b2f(r0.y>>16)     + cf1*b2f(r1.y>>16)     + cf2*b2f(r2.y>>16)     + cf3*b2f(r3.y>>16);
            a[4] += cf0*b2f(r0.z&0xffffu) + cf1*b2f(r1.z&0xffffu) + cf2*b2f(r2.z&0xffffu) + cf3*b2f(r3.z&0xffffu);
            a[5] += cf0*b2f(r0.z>>16)     + cf1*b2f(r1.z>>16)     + cf2*b2f(r2.z>>16)     + cf3*b2f(r3.z>>16);
            a[6] += cf0*b2f(r0.w&0xffffu) + cf1*b2f(r1.w&0xffffu) + cf2*b2f(r2.w&0xffffu) + cf3*b2f(r3.w&0xffffu);
            a[7] += cf0*b2f(r0.w>>16)     + cf1*b2f(r1.w>>16)     + cf2*b2f(r2.w>>16)     + cf3*b2f(r3.w>>16);
        }
        if (ccnt > 64) {
            int e2 = 64;
            for (; e2 + 2 <= ccnt; e2 += 2) {
                const int2 ed_ = edata[cbeg + e2 + half];
                const float cf = __int_as_float(ed_.y);
                const uint4 r = *(const uint4*)(H2 + (size_t)ed_.x * 256 + ci);
                cs += cf;
                a[0] += cf*b2f(r.x&0xffffu); a[1] += cf*b2f(r.x>>16);
                a[2] += cf*b2f(r.y&0xffffu); a[3] += cf*b2f(r.y>>16);
                a[4] += cf*b2f(r.z&0xffffu); a[5] += cf*b2f(r.z>>16);
                a[6] += cf*b2f(r.w&0xffffu); a[7] += cf*b2f(r.w>>16);
            }
            if (e2 < ccnt && half == 0) {
                const int2 ed_ = edata[cbeg + e2];
                const float cf = __int_as_float(ed_.y);
                const uint4 r = *(const uint4*)(H2 + (size_t)ed_.x * 256 + ci);
                cs += cf;
                a[0] += cf*b2f(r.x&0xffffu); a[1] += cf*b2f(r.x>>16);
                a[2] += cf*b2f(r.y&0xffffu); a[3] += cf*b2f(r.y>>16);
                a[4] += cf*b2f(r.z&0xffffu); a[5] += cf*b2f(r.z>>16);
                a[6] += cf*b2f(r.w&0xffffu); a[7] += cf*b2f(r.w>>16);
            }
        }
        cs += __shfl_xor(cs, 32);
#pragma unroll
        for (int j = 0; j < 8; j++) a[j] += __shfl_xor(a[j], 32);
        const float sc = dn * dn, cv = cs + sc;
        const float f0 = a[0] + sc*b2f(rs_.x&0xffffu) + cv*vvA.x + bbA.x;
        const float f1 = a[1] + sc*b2f(rs_.x>>16)     + cv*vvA.y + bbA.y;
        const float f2 = a[2] + sc*b2f(rs_.y&0xffffu) + cv*vvA.z + bbA.z;
        const float f3 = a[3] + sc*b2f(rs_.y>>16)     + cv*vvA.w + bbA.w;
        const float f4 = a[4] + sc*b2f(rs_.z&0xffffu) + cv*vvB.x + bbB.x;
        const float f5 = a[5] + sc*b2f(rs_.z>>16)     + cv*vvB.y + bbB.y;
        const float f6 = a[6] + sc*b2f(rs_.w&0xffffu) + cv*vvB.z + bbB.z;
        const float f7 = a[7] + sc*b2f(rs_.w>>16)     + cv*vvB.w + bbB.w;
        if (half == 0) {
            uint4 o;
            o.x = packb(f0, f1); o.y = packb(f2, f3);
            o.z = packb(f4, f5); o.w = packb(f6, f7);
            *(uint4*)(OutB + (size_t)node * 256 + ci) = o;
        }
        s[0] += f0; q[0] += f0*f0;  s[1] += f1; q[1] += f1*f1;
        s[2] += f2; q[2] += f2*f2;  s[3] += f3; q[3] += f3*f3;
        s[4] += f4; q[4] += f4*f4;  s[5] += f5; q[5] += f5*f5;
        s[6] += f6; q[6] += f6*f6;  s[7] += f7; q[7] += f7*f7;
    }
    ls[t] = 0.f; ls[256 + t] = 0.f;
    __syncthreads();
    if (half == 0) {
#pragma unroll
        for (int j = 0; j < 8; j++) {
            atomicAdd(&ls[ci + j], s[j]);
            atomicAdd(&ls[256 + ci + j], q[j]);
        }
    }
    __syncthreads();
    atomicAdd(&stats[t], ls[t]);
    atomicAdd(&stats[256 + t], ls[256 + t]);
}

// ---------------- virtual node update + v2_next = vx_new @ Wnext ----------------
__global__ void k_vx(const float* __restrict__ pool, const float* __restrict__ vx_old,
                     const float* __restrict__ vnW, const float* __restrict__ vnb,
                     const float* __restrict__ lng, const float* __restrict__ lnb,
                     float* __restrict__ vx_new,
                     const float* __restrict__ Wnext, int ncn, int npn,
                     float* __restrict__ v2n) {
    __shared__ float s[256];
    __shared__ float red[256];
    int t = threadIdx.x;
    float pv = 0.f;
#pragma unroll
    for (int r = 0; r < 8; r++) pv += pool[r * 256 + t];
    s[t] = pv + vx_old[t];
    __syncthreads();
    float y = vnb[t];
    for (int k = 0; k < 256; k++) y += s[k] * vnW[k * 256 + t];
    red[t] = y; __syncthreads();
    for (int off = 128; off > 0; off >>= 1) {
        if (t < off) red[t] += red[t + off];
        __syncthreads();
    }
    float mu = red[0] * (1.f / 256.f);
    __syncthreads();
    float d = y - mu;
    red[t] = d * d; __syncthreads();
    for (int off = 128; off > 0; off >>= 1) {
        if (t < off) red[t] += red[t + off];
        __syncthreads();
    }
    float var = red[0] * (1.f / 256.f);
    float v = fmaxf(d * rsqrtf(var + EPS) * lng[t] + lnb[t], 0.f);
    vx_new[t] = v;
    __syncthreads();
    s[t] = v;
    __syncthreads();
    float acc = 0.f;
    if (t < ncn) {
        for (int k = 0; k < 256; k++) acc += s[k] * Wnext[k * ncn + t];
    }
    if (t < npn) v2n[t] = acc;
}

// ---- layer-2 aggregation + (cs+dn^2)*v2 fold + log_softmax ----
__global__ __launch_bounds__(256) void k_agg2(const u16* __restrict__ H2,
                                              const int* __restrict__ row_start,
                                              const int* __restrict__ counts,
                                              const int2* __restrict__ edata,
                                              const float* __restrict__ dis,
                                              const float* __restrict__ bias,
                                              const float* __restrict__ v2,
                                              float* __restrict__ OutF) {
    const int t = threadIdx.x, wave = t >> 6, lane = t & 63;
    const int half = lane >> 5, hl = lane & 31;
    const bool gact = hl < 24;
    const bool cact = hl < 20;
    const int c0 = 2 * hl;
    float bb0 = 0.f, bb1 = 0.f, vv0 = 0.f, vv1 = 0.f;
    if (cact) {
        float2 bv = *(const float2*)(bias + c0); bb0 = bv.x; bb1 = bv.y;
        float2 vvv = *(const float2*)(v2 + c0);  vv0 = vvv.x; vv1 = vvv.y;
    }
    const int nbase = blockIdx.x * 16 + wave * 4;
    for (int i = 0; i < 4; i++) {
        const int node = nbase + i;
        const int beg = row_start[node], cnt = counts[node];
        const float dn = dis[node];
        float a0 = 0.f, a1 = 0.f, cs = 0.f;
        int e = half;
        for (; e + 6 < cnt; e += 8) {
            int2 ea = edata[beg+e],   eb = edata[beg+e+2];
            int2 ec = edata[beg+e+4], ed = edata[beg+e+6];
            float ca = __int_as_float(ea.y), cb = __int_as_float(eb.y);
            float cc = __int_as_float(ec.y), cd = __int_as_float(ed.y);
            u32 ra = 0, rb = 0, rc = 0, rd = 0;
            if (gact) {
                ra = *(const u32*)(H2 + (size_t)ea.x * COUTP + c0);
                rb = *(const u32*)(H2 + (size_t)eb.x * COUTP + c0);
                rc = *(const u32*)(H2 + (size_t)ec.x * COUTP + c0);
                rd = *(const u32*)(H2 + (size_t)ed.x * COUTP + c0);
            }
            cs += ca + cb + cc + cd;
            a0 += ca*b2f(ra&0xffffu) + cb*b2f(rb&0xffffu) + cc*b2f(rc&0xffffu) + cd*b2f(rd&0xffffu);
            a1 += ca*b2f(ra>>16)     + cb*b2f(rb>>16)     + cc*b2f(rc>>16)     + cd*b2f(rd>>16);
        }
        for (; e < cnt; e += 2) {
            int2 ea = edata[beg+e];
            float ca = __int_as_float(ea.y);
            u32 ra = gact ? *(const u32*)(H2 + (size_t)ea.x * COUTP + c0) : 0u;
            cs += ca;
            a0 += ca*b2f(ra&0xffffu); a1 += ca*b2f(ra>>16);
        }
        a0 += __shfl_xor(a0, 32);
        a1 += __shfl_xor(a1, 32);
        cs += __shfl_xor(cs, 32);
        const float sc = dn * dn;
        u32 rs_ = gact ? *(const u32*)(H2 + (size_t)node * COUTP + c0) : 0u;
        float h0 = a0 + sc*b2f(rs_&0xffffu) + (cs+sc)*vv0 + bb0;
        float h1 = a1 + sc*b2f(rs_>>16)     + (cs+sc)*vv1 + bb1;
        float m = cact ? fmaxf(h0, h1) : -3.0e38f;
#pragma unroll
        for (int off = 16; off > 0; off >>= 1) m = fmaxf(m, __shfl_xor(m, off));
        float ex = cact ? (expf(h0 - m) + expf(h1 - m)) : 0.f;
        float se = ex;
#pragma unroll
        for (int off = 16; off > 0; off >>= 1) se += __shfl_xor(se, off);
        float lg = logf(se);
        if (cact && half == 0) {
            float2 o = {h0 - m - lg, h1 - m - lg};
            *(float2*)(OutF + (size_t)node * COUT + c0) = o;
        }
    }
}

extern "C" void kernel_launch(void* const* d_in, const int* in_sizes, int n_in,
                              void* d_out, int out_size, void* d_ws, size_t ws_size,
                              hipStream_t stream) {
    const float* x   = (const float*)d_in[0];
    const int*   ei  = (const int*)d_in[1];
    const int*   esrc = ei;
    const int*   edst = ei + N_EDGES;
    const float* W0 = (const float*)d_in[2];  const float* b0 = (const float*)d_in[3];
    const float* W1 = (const float*)d_in[4];  const float* b1 = (const float*)d_in[5];
    const float* W2 = (const float*)d_in[6];  const float* b2 = (const float*)d_in[7];
    const float* bg0 = (const float*)d_in[8]; const float* bb0 = (const float*)d_in[9];
    const float* bg1 = (const float*)d_in[10]; const float* bb1 = (const float*)d_in[11];
    const float* vn_emb = (const float*)d_in[12];
    const float* vW0 = (const float*)d_in[13]; const float* vb0 = (const float*)d_in[14];
    const float* lg0 = (const float*)d_in[15]; const float* lb0 = (const float*)d_in[16];
    const float* vW1 = (const float*)d_in[17]; const float* vb1 = (const float*)d_in[18];
    const float* lg1 = (const float*)d_in[19]; const float* lb1 = (const float*)d_in[20];

    char* w = (char*)d_ws;
    auto alloc = [&](size_t bytes) { void* p = (void*)w; w += ((bytes + 255) / 256) * 256; return p; };
    u16* H2    = (u16*)alloc((size_t)N_NODES * 256 * 2);
    u16* OutB  = (u16*)alloc((size_t)N_NODES * 256 * 2);
    int2* edata = (int2*)alloc((size_t)N_EDGES * 8);
    int* counts = (int*)alloc((size_t)N_NODES * 4);
    int* rowst  = (int*)alloc((size_t)N_NODES * 4);
    int* cursor = (int*)alloc((size_t)N_NODES * 4);
    float* dis  = (float*)alloc((size_t)N_NODES * 4);
    u16* Wtb0 = (u16*)alloc(256 * 256 * 2);
    u16* Wtb1 = (u16*)alloc(256 * 256 * 2);
    u16* Wt2b = (u16*)alloc(COUTP * 256 * 2);
    int* scanblk = (int*)alloc(128 * 4);
    float* statsA = (float*)alloc(2560 * 4);   // sum[256], sq[256], pool[8*256]
    float* statsB = (float*)alloc(2560 * 4);
    float* vxA = (float*)alloc(256 * 4);
    float* vxB = (float*)alloc(256 * 4);
    float* v20 = (float*)alloc(256 * 4);
    float* v21 = (float*)alloc(256 * 4);
    float* v22 = (float*)alloc(64 * 4);
    (void)ws_size; (void)in_sizes; (void)n_in; (void)out_size;

    // ---- fused prep: transposes + vecmat + zeroing ----
    k_prep<<<PREP_BLOCKS, 256, 0, stream>>>(W0, W1, W2, Wtb0, Wtb1, Wt2b,
                                            vn_emb, v20, counts, statsA, statsB);
    // ---- graph prep: degrees + CSR ----
    k_count<<<(N_EDGES + 255) / 256, 256, 0, stream>>>(edst, counts);
    k_scan1<<<NSCAN_BLK, 256, 0, stream>>>(counts, rowst, scanblk);
    k_scan3<<<(N_NODES + 255) / 256, 256, 0, stream>>>(rowst, scanblk, cursor, counts, dis);

    // ---- layer 0 GEMM fused with edge fill (independent; fill rides under MFMA) ----
    k_gemm0_fill<<<GEMMBLK + FILLBLK, 512, 0, stream>>>(x, Wtb0, H2,
                                                        esrc, edst, cursor, edata, dis);
    k_agg<<<AGG_BLOCKS, 256, 0, stream>>>(H2, rowst, counts, edata, dis, b0, v20, OutB, statsA);
    // ---- layer 1 (BN0+ReLU+pool fused into gemm A-staging) ----
    k_gemm_bn<<<GEMMBLK, 512, 0, stream>>>(OutB, statsA, bg0, bb0, Wtb1, H2, statsA + 512);
    k_vx<<<1, 256, 0, stream>>>(statsA + 512, vn_emb, vW0, vb0, lg0, lb0, vxA, W1, 256, 256, v21);
    k_agg<<<AGG_BLOCKS, 256, 0, stream>>>(H2, rowst, counts, edata, dis, b1, v21, OutB, statsB);
    // ---- layer 2 ----
    k_gemm2_bn<<<GEMMBLK, 512, 0, stream>>>(OutB, statsB, bg1, bb1, Wt2b, H2, statsB + 512);
    k_vx<<<1, 256, 0, stream>>>(statsB + 512, vxA, vW1, vb1, lg1, lb1, vxB, W2, COUT, COUTP, v22);
    k_agg2<<<N_NODES / 16, 256, 0, stream>>>(H2, rowst, counts, edata, dis, b2, v22, (float*)d_out);
}